// Round 5
// baseline (553.425 us; speedup 1.0000x reference)
//
#include <hip/hip_runtime.h>

// ---------------------------------------------------------------------------
// Mamba2 hybrid block. GEMMs: bf16 MFMA 16x16x32, f32 accumulate, m97-style
// global_load_lds(16B) staging with XOR bank swizzle; small-N GEMMs use
// split-K x4 with f32 atomicAdd epilogue. Scan: 3-phase chunked; phase2 uses
// lane-split state (p,n-quarter per lane) + shuffle reduce -> plain ds_write
// (NO atomics: R4's ds_add same-address serialization was a 1.7x regression).
// ---------------------------------------------------------------------------

#define BB 4
#define LL 1024
#define DMODEL 512
#define DINNER 1024
#define NHEADS 16
#define HEADDIM 64
#define DSTATE 64
#define CONVDIM 1152        // DINNER + 2*DSTATE
#define NPROJ 2192          // D_IN_PROJ
#define NPROJ_PAD 2304      // padded to multiple of 128
#define INTER_T 2816
#define INTER_M 1536
#define NCHUNK 16
#define CHUNK 64

typedef __bf16 bf16x8 __attribute__((ext_vector_type(8)));
typedef float  f32x4  __attribute__((ext_vector_type(4)));
typedef unsigned short u16;
typedef unsigned int   u32;

__device__ __forceinline__ u16 f2bf(float x) {
    union { float f; u32 u; } v; v.f = x;
    u32 u = v.u;
    return (u16)((u + 0x7fffu + ((u >> 16) & 1u)) >> 16);
}
__device__ __forceinline__ float silu_f(float x) {
    return x / (1.f + __expf(-x));
}

// async global->LDS, 16B per lane; LDS dest is wave-uniform base + lane*16
__device__ __forceinline__ void gld_lds16(const u16* g, u16* l) {
    __builtin_amdgcn_global_load_lds(
        (const __attribute__((address_space(1))) unsigned int*)g,
        (__attribute__((address_space(3))) unsigned int*)l, 16, 0, 0);
}

// --------------------------- block-wide sum --------------------------------
__device__ __forceinline__ float block_sum(float v) {
    #pragma unroll
    for (int off = 32; off > 0; off >>= 1) v += __shfl_xor(v, off, 64);
    __shared__ float red[4];
    int w = threadIdx.x >> 6;
    int nwv = blockDim.x >> 6;
    if ((threadIdx.x & 63) == 0) red[w] = v;
    __syncthreads();
    float tot = red[0];
    for (int i = 1; i < nwv; i++) tot += red[i];
    return tot;
}

// --------------------- f32 -> bf16 convert (all weights + hidden) ----------
#define HID_E      2097152LL   // 4096*512
#define INPROJ_P_E 1179648LL   // 2304*512
#define INPROJ_S_E 1122304LL   // 2192*512
#define OUTPROJ_E   524288LL   // 512*1024
#define GUT_E      5767168LL   // 5632*1024
#define DOWNT_E    2883584LL   // 1024*2816
#define GUM_E      1572864LL   // 3072*512
#define DOWNM_E     786432LL   // 512*1536
#define CONV_TOT_E 14811136LL

__global__ __launch_bounds__(256) void convert_all_kernel(
    const float* __restrict__ s_hid, const float* __restrict__ s_inproj,
    const float* __restrict__ s_outproj, const float* __restrict__ s_gut,
    const float* __restrict__ s_downt, const float* __restrict__ s_gum,
    const float* __restrict__ s_downm, u16* __restrict__ dst)
{
    long long idx = (long long)blockIdx.x * 256 + threadIdx.x;
    long long e = idx * 4;
    if (e >= CONV_TOT_E) return;
    const float* src; long long off, nsrc;
    long long c0 = HID_E;
    long long c1 = c0 + INPROJ_P_E;
    long long c2 = c1 + OUTPROJ_E;
    long long c3 = c2 + GUT_E;
    long long c4 = c3 + DOWNT_E;
    long long c5 = c4 + GUM_E;
    if      (e < c0) { src = s_hid;     off = e;      nsrc = HID_E; }
    else if (e < c1) { src = s_inproj;  off = e - c0; nsrc = INPROJ_S_E; }
    else if (e < c2) { src = s_outproj; off = e - c1; nsrc = OUTPROJ_E; }
    else if (e < c3) { src = s_gut;     off = e - c2; nsrc = GUT_E; }
    else if (e < c4) { src = s_downt;   off = e - c3; nsrc = DOWNT_E; }
    else if (e < c5) { src = s_gum;     off = e - c4; nsrc = GUM_E; }
    else             { src = s_downm;   off = e - c5; nsrc = DOWNM_E; }
    ushort4 r;
    if (off < nsrc) {
        float4 v = *reinterpret_cast<const float4*>(src + off);
        r.x = f2bf(v.x); r.y = f2bf(v.y); r.z = f2bf(v.z); r.w = f2bf(v.w);
    } else {
        r.x = 0; r.y = 0; r.z = 0; r.w = 0;
    }
    *reinterpret_cast<ushort4*>(dst + e) = r;
}

// ----------------------------- bf16 MFMA GEMM ------------------------------
// C[M,N] = A[M,K] * W[N,K]^T. 128x128 tile, 4 waves of 64x64 (4x4 MFMAs).
// global_load_lds staging (no pad; XOR chunk swizzle vs bank conflicts).
template<bool ATOMIC>
__device__ __forceinline__ void gemm_bt_body(
    const u16* __restrict__ A, const u16* __restrict__ W,
    float* __restrict__ C, int M, int N, int K, int kBase, int kLen)
{
    __shared__ u16 As[128 * 32];
    __shared__ u16 Bs[128 * 32];
    int tid = threadIdx.x;
    int m0 = blockIdx.y * 128, n0 = blockIdx.x * 128;
    int wave = tid >> 6, lane = tid & 63;
    int wm = (wave >> 1) * 64, wn = (wave & 1) * 64;
    int lrow = lane & 15;
    int kq = lane >> 4;
    int kx = (lrow & 3) ^ ((lrow >> 2) & 3);
    int ko = (kq ^ kx) * 8;           // swizzled LDS chunk offset for frags

    int rL = lane >> 2, cL = lane & 3;
    int cG = cL ^ ((rL & 3) ^ ((rL >> 2) & 3));
    int R0 = wave * 32 + rL;
    int R1 = R0 + 16;
    const u16* gA0 = A + (size_t)(m0 + R0) * K + kBase + cG * 8;
    const u16* gA1 = A + (size_t)(m0 + R1) * K + kBase + cG * 8;
    const u16* gB0 = W + (size_t)(n0 + R0) * K + kBase + cG * 8;
    const u16* gB1 = W + (size_t)(n0 + R1) * K + kBase + cG * 8;
    u16* lA0 = &As[(wave * 32) * 32];
    u16* lA1 = &As[(wave * 32 + 16) * 32];
    u16* lB0 = &Bs[(wave * 32) * 32];
    u16* lB1 = &Bs[(wave * 32 + 16) * 32];

    f32x4 acc[4][4];
    #pragma unroll
    for (int i = 0; i < 4; i++)
        #pragma unroll
        for (int j = 0; j < 4; j++) {
            acc[i][j][0] = 0.f; acc[i][j][1] = 0.f;
            acc[i][j][2] = 0.f; acc[i][j][3] = 0.f;
        }

    for (int kt = 0; kt < kLen; kt += 32) {
        __syncthreads();
        gld_lds16(gA0 + kt, lA0);
        gld_lds16(gA1 + kt, lA1);
        gld_lds16(gB0 + kt, lB0);
        gld_lds16(gB1 + kt, lB1);
        __syncthreads();
        bf16x8 af[4], bfr[4];
        #pragma unroll
        for (int i = 0; i < 4; i++) {
            af[i]  = *reinterpret_cast<const bf16x8*>(&As[(wm + i * 16 + lrow) * 32 + ko]);
            bfr[i] = *reinterpret_cast<const bf16x8*>(&Bs[(wn + i * 16 + lrow) * 32 + ko]);
        }
        #pragma unroll
        for (int i = 0; i < 4; i++)
            #pragma unroll
            for (int j = 0; j < 4; j++)
                acc[i][j] = __builtin_amdgcn_mfma_f32_16x16x32_bf16(af[i], bfr[j], acc[i][j], 0, 0, 0);
    }

    // C/D layout: col = lane&15, row = (lane>>4)*4 + reg
    int rbase = m0 + wm + kq * 4;
    int cbase = n0 + wn + lrow;
    #pragma unroll
    for (int i = 0; i < 4; i++)
        #pragma unroll
        for (int j = 0; j < 4; j++)
            #pragma unroll
            for (int r = 0; r < 4; r++) {
                float* p = &C[(size_t)(rbase + i * 16 + r) * N + cbase + j * 16];
                if (ATOMIC) atomicAdd(p, acc[i][j][r]);
                else        *p = acc[i][j][r];
            }
}

__global__ __launch_bounds__(256) void gemm_bt(
    const u16* __restrict__ A, const u16* __restrict__ W,
    float* __restrict__ C, int M, int N, int K)
{
    gemm_bt_body<false>(A, W, C, M, N, K, 0, K);
}

__global__ __launch_bounds__(256) void gemm_bt_sk(
    const u16* __restrict__ A, const u16* __restrict__ W,
    float* __restrict__ C, int M, int N, int K, int kLen)
{
    gemm_bt_body<true>(A, W, C, M, N, K, blockIdx.z * kLen, kLen);
}

// ----------------- conv (depthwise, causal, width 4) + dt ------------------
__global__ __launch_bounds__(256) void conv_dt_kernel(
    const float* __restrict__ zx, const float* __restrict__ conv_w,
    const float* __restrict__ conv_b, const float* __restrict__ dt_bias,
    float* __restrict__ convout, float* __restrict__ dtbuf)
{
    int idx = blockIdx.x * 256 + threadIdx.x;   // over 4096*1168
    int bl = idx / 1168;
    int c  = idx - bl * 1168;
    int l  = bl & (LL - 1);
    if (c < CONVDIM) {
        const float* col = zx + (size_t)bl * NPROJ_PAD + DINNER + c;
        float acc = conv_b[c];
        #pragma unroll
        for (int i = 0; i < 4; i++) {
            int lt = l - 3 + i;
            float v = (lt >= 0) ? col[(long long)(lt - l) * NPROJ_PAD] : 0.f;
            acc = fmaf(v, conv_w[c * 4 + i], acc);
        }
        convout[(size_t)bl * CONVDIM + c] = silu_f(acc);
    } else {
        int h = c - CONVDIM;
        float v = zx[(size_t)bl * NPROJ_PAD + 2176 + h] + dt_bias[h];
        float sp = (v > 20.f) ? v : log1pf(__expf(v));
        dtbuf[(size_t)bl * NHEADS + h] = sp;
    }
}

// ----------------------- chunked SSM scan: phase 1 -------------------------
// block = (((b*16+h)*4+nq)*16+c); lane p; 64 steps from zero state.
__global__ __launch_bounds__(64) void scan_phase1(
    const float* __restrict__ convout, const float* __restrict__ dtbuf,
    const float* __restrict__ A_log, float* __restrict__ Sc,
    float* __restrict__ Ptot)
{
    int blk = blockIdx.x;
    int c   = blk & 15;
    int bhq = blk >> 4;
    int nq  = bhq & 3;
    int bh  = bhq >> 2;
    int b = bh >> 4, h = bh & 15;
    int p = threadIdx.x;
    float Ah = -__expf(A_log[h]);
    size_t base = ((size_t)b * LL + (size_t)c * CHUNK) * CONVDIM;
    const float* xb = convout + base + h * HEADDIM + p;
    const float* Bb = convout + base + DINNER + nq * 16;
    const float* db = dtbuf + ((size_t)b * LL + (size_t)c * CHUNK) * NHEADS + h;

    float s[16];
    #pragma unroll
    for (int j = 0; j < 16; j++) s[j] = 0.f;
    float dtsum = 0.f;

    float dtc = db[0], xvc = xb[0];
    float Bv[16];
    #pragma unroll
    for (int j = 0; j < 16; j++) Bv[j] = Bb[j];

    for (int t = 0; t < CHUNK; ++t) {
        float dt = dtc, xv = xvc;
        float Bl[16];
        #pragma unroll
        for (int j = 0; j < 16; j++) Bl[j] = Bv[j];
        int tn = (t < CHUNK - 1) ? t + 1 : CHUNK - 1;
        dtc = db[(size_t)tn * NHEADS];
        xvc = xb[(size_t)tn * CONVDIM];
        const float* Bt = Bb + (size_t)tn * CONVDIM;
        #pragma unroll
        for (int j = 0; j < 16; j++) Bv[j] = Bt[j];
        float dA = __expf(dt * Ah);
        dtsum += dt;
        float coef = dt * xv;
        #pragma unroll
        for (int j = 0; j < 16; j++) s[j] = fmaf(s[j], dA, coef * Bl[j]);
    }
    float* So = Sc + (size_t)blk * 1024 + p * 16;
    #pragma unroll
    for (int q = 0; q < 4; q++) {
        float4 v; v.x = s[q*4]; v.y = s[q*4+1]; v.z = s[q*4+2]; v.w = s[q*4+3];
        *reinterpret_cast<float4*>(So + q * 4) = v;
    }
    if (nq == 0 && p == 0) Ptot[bh * 16 + c] = __expf(Ah * dtsum);
}

// ----------------------- chunked SSM scan: phase 2 -------------------------
__global__ __launch_bounds__(64) void scan_combine(
    const float* __restrict__ Sc, const float* __restrict__ Ptot,
    float* __restrict__ Sinit)
{
    int blk = blockIdx.x;
    int bh = blk >> 2;
    int p = threadIdx.x;
    float carry[16];
    #pragma unroll
    for (int j = 0; j < 16; j++) carry[j] = 0.f;
    for (int c = 0; c < NCHUNK; ++c) {
        size_t row = ((size_t)blk * 16 + c) * 1024 + p * 16;
        float* o = Sinit + row;
        #pragma unroll
        for (int j = 0; j < 16; j++) o[j] = carry[j];
        float P = Ptot[bh * 16 + c];
        const float* si = Sc + row;
        #pragma unroll
        for (int j = 0; j < 16; j++) carry[j] = fmaf(carry[j], P, si[j]);
    }
}

// ----------------------- chunked SSM scan: phase 3 -------------------------
// One 256-thread block per (b,h,chunk). Wave w owns p in [w*16, w*16+16);
// lane = pl*4+nn owns (p = w*16+pl, n in [nn*16, nn*16+16)). y reduction over
// n = 2x shfl_xor across the 4 nn-lanes, then plain ds_write by nn==0 lanes.
// No atomics anywhere. Each ylds slot written exactly once.
__global__ __launch_bounds__(256) void scan_phase2(
    const float* __restrict__ convout, const float* __restrict__ dtbuf,
    const float* __restrict__ A_log, const float* __restrict__ Sinit,
    float* __restrict__ ybuf)
{
    __shared__ float ylds[CHUNK * 64];   // [t][p] 16 KB
    int blk = blockIdx.x;                // (b*16+h)*16 + c
    int c   = blk & 15;
    int bh  = blk >> 4;
    int b = bh >> 4, h = bh & 15;
    int w    = threadIdx.x >> 6;
    int lane = threadIdx.x & 63;
    int pl = lane >> 2;                  // 0..15
    int nn = lane & 3;                   // n-quarter
    int p  = w * 16 + pl;
    float Ah = -__expf(A_log[h]);

    size_t base = ((size_t)b * LL + (size_t)c * CHUNK) * CONVDIM;
    const float* xb = convout + base + h * HEADDIM + p;
    const float* Bb = convout + base + DINNER + nn * 16;
    const float* Cb = Bb + DSTATE;
    const float* db = dtbuf + ((size_t)b * LL + (size_t)c * CHUNK) * NHEADS + h;

    float s[16];
    const float* si = Sinit + (((size_t)(bh * 4 + nn) * 16 + c) * 1024) + p * 16;
    #pragma unroll
    for (int j = 0; j < 16; j++) s[j] = si[j];

    float dtc = db[0], xvc = xb[0];
    float Bv[16], Cv[16];
    #pragma unroll
    for (int j = 0; j < 16; j++) { Bv[j] = Bb[j]; Cv[j] = Cb[j]; }

    for (int t = 0; t < CHUNK; ++t) {
        float dt = dtc, xv = xvc;
        float Bl[16], Cl[16];
        #pragma unroll
        for (int j = 0; j < 16; j++) { Bl[j] = Bv[j]; Cl[j] = Cv[j]; }
        int tn = (t < CHUNK - 1) ? t + 1 : CHUNK - 1;
        dtc = db[(size_t)tn * NHEADS];
        xvc = xb[(size_t)tn * CONVDIM];
        const float* Bt = Bb + (size_t)tn * CONVDIM;
        const float* Ct = Cb + (size_t)tn * CONVDIM;
        #pragma unroll
        for (int j = 0; j < 16; j++) { Bv[j] = Bt[j]; Cv[j] = Ct[j]; }
        float dA = __expf(dt * Ah);
        float coef = dt * xv;
        float yacc = 0.f;
        #pragma unroll
        for (int j = 0; j < 16; j++) {
            s[j] = fmaf(s[j], dA, coef * Bl[j]);
            yacc = fmaf(s[j], Cl[j], yacc);
        }
        // reduce over the 4 nn-lanes (bits 0-1 of lane)
        yacc += __shfl_xor(yacc, 1, 64);
        yacc += __shfl_xor(yacc, 2, 64);
        if (nn == 0) ylds[t * 64 + p] = yacc;   // 16 consecutive dwords/wave
    }
    __syncthreads();
    float* yb = ybuf + ((size_t)b * LL + (size_t)c * CHUNK) * DINNER + h * HEADDIM;
    for (int i = threadIdx.x; i < CHUNK * 64; i += 256) {
        int t = i >> 6, pp = i & 63;
        yb[(size_t)t * DINNER + pp] = ylds[i];
    }
}

// --------------------- gated RMSNorm (y+xD)*silu(z) ------------------------
__global__ __launch_bounds__(256) void gated_rms_kernel(
    const float* __restrict__ ybuf, const float* __restrict__ convout,
    const float* __restrict__ zx, const float* __restrict__ Dv,
    const float* __restrict__ norm_w, u16* __restrict__ gout)
{
    int bl = blockIdx.x;
    int c = threadIdx.x * 4;
    float4 yv = *reinterpret_cast<const float4*>(ybuf + (size_t)bl * DINNER + c);
    float4 xv = *reinterpret_cast<const float4*>(convout + (size_t)bl * CONVDIM + c);
    float4 zv = *reinterpret_cast<const float4*>(zx + (size_t)bl * NPROJ_PAD + c);
    float Dh = Dv[c >> 6];
    float g0 = (yv.x + xv.x * Dh) * silu_f(zv.x);
    float g1 = (yv.y + xv.y * Dh) * silu_f(zv.y);
    float g2 = (yv.z + xv.z * Dh) * silu_f(zv.z);
    float g3 = (yv.w + xv.w * Dh) * silu_f(zv.w);
    float tot = block_sum(g0 * g0 + g1 * g1 + g2 * g2 + g3 * g3);
    float sc = rsqrtf(tot * (1.f / DINNER) + 1e-5f);
    float4 nw = *reinterpret_cast<const float4*>(norm_w + c);
    ushort4 o;
    o.x = f2bf(g0 * sc * nw.x); o.y = f2bf(g1 * sc * nw.y);
    o.z = f2bf(g2 * sc * nw.z); o.w = f2bf(g3 * sc * nw.w);
    *reinterpret_cast<ushort4*>(gout + (size_t)bl * DINNER + c) = o;
}

// ---------------- residual + RMSNorm (no weight), f32 out ------------------
__global__ void residual_rms_kernel(
    const float* __restrict__ a, const float* __restrict__ b,
    float* __restrict__ outf, int ncols)
{
    int row = blockIdx.x;
    int c = threadIdx.x * 4;
    float4 va = *reinterpret_cast<const float4*>(a + (size_t)row * ncols + c);
    float4 vb = *reinterpret_cast<const float4*>(b + (size_t)row * ncols + c);
    float v0 = va.x + vb.x, v1 = va.y + vb.y, v2 = va.z + vb.z, v3 = va.w + vb.w;
    float tot = block_sum(v0 * v0 + v1 * v1 + v2 * v2 + v3 * v3);
    float sc = rsqrtf(tot / (float)ncols + 1e-5f);
    float4 o; o.x = v0 * sc; o.y = v1 * sc; o.z = v2 * sc; o.w = v3 * sc;
    *reinterpret_cast<float4*>(outf + (size_t)row * ncols + c) = o;
}

// ------------- transpose per batch: in (R,C) -> out (C,R), dual write ------
__global__ __launch_bounds__(256) void transpose_dual_kernel(
    const float* __restrict__ in, u16* __restrict__ outb,
    float* __restrict__ outf, int R, int C)
{
    __shared__ float tile[32][33];
    int b = blockIdx.z;
    int c0 = blockIdx.x * 32, r0 = blockIdx.y * 32;
    const float* ip = in + (size_t)b * R * C;
    for (int i = threadIdx.y; i < 32; i += 8)
        tile[i][threadIdx.x] = ip[(size_t)(r0 + i) * C + c0 + threadIdx.x];
    __syncthreads();
    size_t ob = (size_t)b * R * C;
    for (int i = threadIdx.y; i < 32; i += 8) {
        float v = tile[threadIdx.x][i];
        size_t oi = ob + (size_t)(c0 + i) * R + r0 + threadIdx.x;
        outf[oi] = v;
        outb[oi] = f2bf(v);
    }
}

// ------------------------------ SwiGLU -------------------------------------
__global__ __launch_bounds__(256) void swiglu_kernel(
    const float* __restrict__ t, u16* __restrict__ act, int rows, int inter)
{
    int idx = blockIdx.x * 256 + threadIdx.x;
    if (idx >= rows * inter) return;
    int r = idx / inter, c = idx - r * inter;
    float g = t[(size_t)r * 2 * inter + c];
    float u = t[(size_t)r * 2 * inter + inter + c];
    act[idx] = f2bf(silu_f(g) * u);
}

// ---------------------------------------------------------------------------
extern "C" void kernel_launch(void* const* d_in, const int* in_sizes, int n_in,
                              void* d_out, int out_size, void* d_ws, size_t ws_size,
                              hipStream_t stream)
{
    const float* hid      = (const float*)d_in[0];
    const float* in_proj  = (const float*)d_in[1];
    const float* conv_w   = (const float*)d_in[2];
    const float* conv_b   = (const float*)d_in[3];
    const float* dt_bias  = (const float*)d_in[4];
    const float* A_log    = (const float*)d_in[5];
    const float* Dv       = (const float*)d_in[6];
    const float* norm_w   = (const float*)d_in[7];
    const float* out_proj = (const float*)d_in[8];
    const float* gu_t     = (const float*)d_in[9];
    const float* down_t   = (const float*)d_in[10];
    const float* gu_m     = (const float*)d_in[11];
    const float* down_m   = (const float*)d_in[12];
    float* outp = (float*)d_out;

    char* ws = (char*)d_ws;
    u16* bf        = (u16*)ws;
    u16* hid_bf    = bf;
    u16* w_inproj  = bf + HID_E;
    u16* w_outproj = w_inproj + INPROJ_P_E;
    u16* w_gut     = w_outproj + OUTPROJ_E;
    u16* w_downt   = w_gut + GUT_E;
    u16* w_gum     = w_downt + DOWNT_E;
    u16* w_downm   = w_gum + GUM_E;
    size_t o = (size_t)(CONV_TOT_E * 2);
    auto alloc = [&](size_t bytes) { size_t r = o; o = (o + bytes + 255) & ~(size_t)255; return r; };
    size_t dt_off  = alloc(4096 * 16 * 4);
    size_t g_off   = alloc((size_t)4096 * 1024 * 2);
    size_t out2_off= alloc((size_t)4096 * 512 * 4);
    size_t h1_off  = alloc((size_t)4096 * 512 * 4);
    size_t xtb_off = alloc((size_t)2048 * 1024 * 2);
    size_t xtf_off = alloc((size_t)2048 * 1024 * 4);
    size_t act1_off= alloc((size_t)2048 * 2816 * 2);
    size_t t2_off  = alloc((size_t)2048 * 1024 * 4);
    size_t x2_off  = alloc((size_t)2048 * 1024 * 4);
    size_t h2b_off = alloc((size_t)4096 * 512 * 2);
    size_t h2f_off = alloc((size_t)4096 * 512 * 4);
    size_t act2_off= alloc((size_t)4096 * 1536 * 2);
    size_t t4_off  = alloc((size_t)4096 * 512 * 4);
    size_t Sc_off  = alloc((size_t)4096 * 1024 * 4);
    size_t Si_off  = alloc((size_t)4096 * 1024 * 4);
    size_t Pt_off  = alloc(1024 * 4);
    // overlay region: {zxbcdt, convout, ybuf} live until gated_rms; t1/t3 after
    size_t R_off   = o;
    size_t zx_off  = R_off;
    size_t cv_off  = zx_off + (size_t)4096 * NPROJ_PAD * 4;
    size_t y_off   = cv_off + (size_t)4096 * CONVDIM * 4;
    size_t t1_off  = R_off;
    size_t t3_off  = R_off;

    float* zx      = (float*)(ws + zx_off);
    float* convout = (float*)(ws + cv_off);
    float* ybuf    = (float*)(ws + y_off);
    float* dtbuf   = (float*)(ws + dt_off);
    u16*   g_bf    = (u16*)(ws + g_off);
    float* out2    = (float*)(ws + out2_off);
    float* h1      = (float*)(ws + h1_off);
    u16*   xt_bf   = (u16*)(ws + xtb_off);
    float* xt_f    = (float*)(ws + xtf_off);
    float* t1      = (float*)(ws + t1_off);
    u16*   act1    = (u16*)(ws + act1_off);
    float* t2      = (float*)(ws + t2_off);
    float* x2      = (float*)(ws + x2_off);
    u16*   h2_bf   = (u16*)(ws + h2b_off);
    float* h2_f    = (float*)(ws + h2f_off);
    float* t3      = (float*)(ws + t3_off);
    u16*   act2    = (u16*)(ws + act2_off);
    float* t4      = (float*)(ws + t4_off);
    float* Sc      = (float*)(ws + Sc_off);
    float* Sinit   = (float*)(ws + Si_off);
    float* Ptot    = (float*)(ws + Pt_off);

    // 0) zero split-K GEMM outputs (atomic accumulation)
    hipMemsetAsync(out2, 0, (size_t)4096 * 512 * 4, stream);
    hipMemsetAsync(t2,   0, (size_t)2048 * 1024 * 4, stream);
    hipMemsetAsync(t4,   0, (size_t)4096 * 512 * 4, stream);

    // 1) convert weights + hidden to bf16
    convert_all_kernel<<<14464, 256, 0, stream>>>(
        hid, in_proj, out_proj, gu_t, down_t, gu_m, down_m, bf);

    // 2) zxbcdt = hidden @ in_proj^T  (576 blocks)
    gemm_bt<<<dim3(NPROJ_PAD / 128, 4096 / 128), 256, 0, stream>>>(
        hid_bf, w_inproj, zx, 4096, NPROJ_PAD, 512);

    // 3) conv + dt
    conv_dt_kernel<<<18688, 256, 0, stream>>>(zx, conv_w, conv_b, dt_bias, convout, dtbuf);

    // 4) chunked SSM scan
    scan_phase1<<<4096, 64, 0, stream>>>(convout, dtbuf, A_log, Sc, Ptot);
    scan_combine<<<256, 64, 0, stream>>>(Sc, Ptot, Sinit);
    scan_phase2<<<1024, 256, 0, stream>>>(convout, dtbuf, A_log, Sinit, ybuf);

    // 5) gated RMSNorm -> bf16
    gated_rms_kernel<<<4096, 256, 0, stream>>>(ybuf, convout, zx, Dv, norm_w, g_bf);

    // 6) out_proj GEMM, split-K x4 (512 blocks)
    gemm_bt_sk<<<dim3(512 / 128, 4096 / 128, 4), 256, 0, stream>>>(
        g_bf, w_outproj, out2, 4096, 512, 1024, 256);

    // 7) h1 = rms(hidden + out2)
    residual_rms_kernel<<<4096, 128, 0, stream>>>(hid, out2, h1, 512);

    // 8) transpose (B,1024,512) -> (B,512,1024)
    transpose_dual_kernel<<<dim3(16, 32, 4), dim3(32, 8), 0, stream>>>(h1, xt_bf, xt_f, 1024, 512);

    // 9) token MLP: t1 = xt @ gu_t^T (704 blocks)
    gemm_bt<<<dim3(5632 / 128, 2048 / 128), 256, 0, stream>>>(xt_bf, w_gut, t1, 2048, 5632, 1024);

    // 10) swiglu -> act1 bf16
    swiglu_kernel<<<22528, 256, 0, stream>>>(t1, act1, 2048, 2816);

    // 11) t2 = act1 @ down_t^T, split-K x4 (512 blocks)
    gemm_bt_sk<<<dim3(1024 / 128, 2048 / 128, 4), 256, 0, stream>>>(
        act1, w_downt, t2, 2048, 1024, 2816, 704);

    // 12) x2 = rms(xt_f + t2)
    residual_rms_kernel<<<2048, 256, 0, stream>>>(xt_f, t2, x2, 1024);

    // 13) transpose back (B,512,1024) -> (B,1024,512)
    transpose_dual_kernel<<<dim3(32, 16, 4), dim3(32, 8), 0, stream>>>(x2, h2_bf, h2_f, 512, 1024);

    // 14) channel MLP: t3 = h2 @ gu_m^T (768 blocks)
    gemm_bt<<<dim3(3072 / 128, 4096 / 128), 256, 0, stream>>>(h2_bf, w_gum, t3, 4096, 3072, 512);

    // 15) swiglu -> act2 bf16
    swiglu_kernel<<<24576, 256, 0, stream>>>(t3, act2, 4096, 1536);

    // 16) t4 = act2 @ down_m^T, split-K x4 (512 blocks)
    gemm_bt_sk<<<dim3(512 / 128, 4096 / 128, 4), 256, 0, stream>>>(
        act2, w_downm, t4, 4096, 512, 1536, 384);

    // 17) out = rms(h2_f + t4)
    residual_rms_kernel<<<4096, 128, 0, stream>>>(h2_f, t4, outp, 512);
}

// Round 6
// 511.051 us; speedup vs baseline: 1.0829x; 1.0829x over previous
//
#include <hip/hip_runtime.h>

// ---------------------------------------------------------------------------
// Mamba2 hybrid block. GEMMs: bf16 MFMA 16x16x32, f32 accumulate, m97-style
// global_load_lds(16B) staging with XOR bank swizzle; small-N GEMMs use
// split-K x4 with f32 atomicAdd epilogue. Scan: 3-phase chunked; phase2 splits
// n into HALVES per block (32 states/lane) so y is per-lane complete -> plain
// coalesced stores into two partial buffers summed by gated_rms.
// (R4 lesson: ds_add same-address serializes; R5 lesson: per-step shfl chains
//  serialize on the LDS pipe. No cross-lane ops in the scan loop, ever.)
// ---------------------------------------------------------------------------

#define BB 4
#define LL 1024
#define DMODEL 512
#define DINNER 1024
#define NHEADS 16
#define HEADDIM 64
#define DSTATE 64
#define CONVDIM 1152        // DINNER + 2*DSTATE
#define NPROJ 2192          // D_IN_PROJ
#define NPROJ_PAD 2304      // padded to multiple of 128
#define INTER_T 2816
#define INTER_M 1536
#define NCHUNK 16
#define CHUNK 64

typedef __bf16 bf16x8 __attribute__((ext_vector_type(8)));
typedef float  f32x4  __attribute__((ext_vector_type(4)));
typedef unsigned short u16;
typedef unsigned int   u32;

__device__ __forceinline__ u16 f2bf(float x) {
    union { float f; u32 u; } v; v.f = x;
    u32 u = v.u;
    return (u16)((u + 0x7fffu + ((u >> 16) & 1u)) >> 16);
}
__device__ __forceinline__ float silu_f(float x) {
    return x / (1.f + __expf(-x));
}

// async global->LDS, 16B per lane; LDS dest is wave-uniform base + lane*16
__device__ __forceinline__ void gld_lds16(const u16* g, u16* l) {
    __builtin_amdgcn_global_load_lds(
        (const __attribute__((address_space(1))) unsigned int*)g,
        (__attribute__((address_space(3))) unsigned int*)l, 16, 0, 0);
}

// --------------------------- block-wide sum --------------------------------
__device__ __forceinline__ float block_sum(float v) {
    #pragma unroll
    for (int off = 32; off > 0; off >>= 1) v += __shfl_xor(v, off, 64);
    __shared__ float red[4];
    int w = threadIdx.x >> 6;
    int nwv = blockDim.x >> 6;
    if ((threadIdx.x & 63) == 0) red[w] = v;
    __syncthreads();
    float tot = red[0];
    for (int i = 1; i < nwv; i++) tot += red[i];
    return tot;
}

// --------------------- f32 -> bf16 convert (all weights + hidden) ----------
#define HID_E      2097152LL   // 4096*512
#define INPROJ_P_E 1179648LL   // 2304*512
#define INPROJ_S_E 1122304LL   // 2192*512
#define OUTPROJ_E   524288LL   // 512*1024
#define GUT_E      5767168LL   // 5632*1024
#define DOWNT_E    2883584LL   // 1024*2816
#define GUM_E      1572864LL   // 3072*512
#define DOWNM_E     786432LL   // 512*1536
#define CONV_TOT_E 14811136LL

__global__ __launch_bounds__(256) void convert_all_kernel(
    const float* __restrict__ s_hid, const float* __restrict__ s_inproj,
    const float* __restrict__ s_outproj, const float* __restrict__ s_gut,
    const float* __restrict__ s_downt, const float* __restrict__ s_gum,
    const float* __restrict__ s_downm, u16* __restrict__ dst)
{
    long long idx = (long long)blockIdx.x * 256 + threadIdx.x;
    long long e = idx * 4;
    if (e >= CONV_TOT_E) return;
    const float* src; long long off, nsrc;
    long long c0 = HID_E;
    long long c1 = c0 + INPROJ_P_E;
    long long c2 = c1 + OUTPROJ_E;
    long long c3 = c2 + GUT_E;
    long long c4 = c3 + DOWNT_E;
    long long c5 = c4 + GUM_E;
    if      (e < c0) { src = s_hid;     off = e;      nsrc = HID_E; }
    else if (e < c1) { src = s_inproj;  off = e - c0; nsrc = INPROJ_S_E; }
    else if (e < c2) { src = s_outproj; off = e - c1; nsrc = OUTPROJ_E; }
    else if (e < c3) { src = s_gut;     off = e - c2; nsrc = GUT_E; }
    else if (e < c4) { src = s_downt;   off = e - c3; nsrc = DOWNT_E; }
    else if (e < c5) { src = s_gum;     off = e - c4; nsrc = GUM_E; }
    else             { src = s_downm;   off = e - c5; nsrc = DOWNM_E; }
    ushort4 r;
    if (off < nsrc) {
        float4 v = *reinterpret_cast<const float4*>(src + off);
        r.x = f2bf(v.x); r.y = f2bf(v.y); r.z = f2bf(v.z); r.w = f2bf(v.w);
    } else {
        r.x = 0; r.y = 0; r.z = 0; r.w = 0;
    }
    *reinterpret_cast<ushort4*>(dst + e) = r;
}

// ----------------------------- bf16 MFMA GEMM ------------------------------
// C[M,N] = A[M,K] * W[N,K]^T. 128x128 tile, 4 waves of 64x64 (4x4 MFMAs).
// global_load_lds staging (no pad; XOR chunk swizzle vs bank conflicts).
template<bool ATOMIC>
__device__ __forceinline__ void gemm_bt_body(
    const u16* __restrict__ A, const u16* __restrict__ W,
    float* __restrict__ C, int M, int N, int K, int kBase, int kLen)
{
    __shared__ u16 As[128 * 32];
    __shared__ u16 Bs[128 * 32];
    int tid = threadIdx.x;
    int m0 = blockIdx.y * 128, n0 = blockIdx.x * 128;
    int wave = tid >> 6, lane = tid & 63;
    int wm = (wave >> 1) * 64, wn = (wave & 1) * 64;
    int lrow = lane & 15;
    int kq = lane >> 4;
    int kx = (lrow & 3) ^ ((lrow >> 2) & 3);
    int ko = (kq ^ kx) * 8;           // swizzled LDS chunk offset for frags

    int rL = lane >> 2, cL = lane & 3;
    int cG = cL ^ ((rL & 3) ^ ((rL >> 2) & 3));
    int R0 = wave * 32 + rL;
    int R1 = R0 + 16;
    const u16* gA0 = A + (size_t)(m0 + R0) * K + kBase + cG * 8;
    const u16* gA1 = A + (size_t)(m0 + R1) * K + kBase + cG * 8;
    const u16* gB0 = W + (size_t)(n0 + R0) * K + kBase + cG * 8;
    const u16* gB1 = W + (size_t)(n0 + R1) * K + kBase + cG * 8;
    u16* lA0 = &As[(wave * 32) * 32];
    u16* lA1 = &As[(wave * 32 + 16) * 32];
    u16* lB0 = &Bs[(wave * 32) * 32];
    u16* lB1 = &Bs[(wave * 32 + 16) * 32];

    f32x4 acc[4][4];
    #pragma unroll
    for (int i = 0; i < 4; i++)
        #pragma unroll
        for (int j = 0; j < 4; j++) {
            acc[i][j][0] = 0.f; acc[i][j][1] = 0.f;
            acc[i][j][2] = 0.f; acc[i][j][3] = 0.f;
        }

    for (int kt = 0; kt < kLen; kt += 32) {
        __syncthreads();
        gld_lds16(gA0 + kt, lA0);
        gld_lds16(gA1 + kt, lA1);
        gld_lds16(gB0 + kt, lB0);
        gld_lds16(gB1 + kt, lB1);
        __syncthreads();
        bf16x8 af[4], bfr[4];
        #pragma unroll
        for (int i = 0; i < 4; i++) {
            af[i]  = *reinterpret_cast<const bf16x8*>(&As[(wm + i * 16 + lrow) * 32 + ko]);
            bfr[i] = *reinterpret_cast<const bf16x8*>(&Bs[(wn + i * 16 + lrow) * 32 + ko]);
        }
        #pragma unroll
        for (int i = 0; i < 4; i++)
            #pragma unroll
            for (int j = 0; j < 4; j++)
                acc[i][j] = __builtin_amdgcn_mfma_f32_16x16x32_bf16(af[i], bfr[j], acc[i][j], 0, 0, 0);
    }

    // C/D layout: col = lane&15, row = (lane>>4)*4 + reg
    int rbase = m0 + wm + kq * 4;
    int cbase = n0 + wn + lrow;
    #pragma unroll
    for (int i = 0; i < 4; i++)
        #pragma unroll
        for (int j = 0; j < 4; j++)
            #pragma unroll
            for (int r = 0; r < 4; r++) {
                float* p = &C[(size_t)(rbase + i * 16 + r) * N + cbase + j * 16];
                if (ATOMIC) atomicAdd(p, acc[i][j][r]);
                else        *p = acc[i][j][r];
            }
}

__global__ __launch_bounds__(256) void gemm_bt(
    const u16* __restrict__ A, const u16* __restrict__ W,
    float* __restrict__ C, int M, int N, int K)
{
    gemm_bt_body<false>(A, W, C, M, N, K, 0, K);
}

__global__ __launch_bounds__(256) void gemm_bt_sk(
    const u16* __restrict__ A, const u16* __restrict__ W,
    float* __restrict__ C, int M, int N, int K, int kLen)
{
    gemm_bt_body<true>(A, W, C, M, N, K, blockIdx.z * kLen, kLen);
}

// ----------------- conv (depthwise, causal, width 4) + dt ------------------
__global__ __launch_bounds__(256) void conv_dt_kernel(
    const float* __restrict__ zx, const float* __restrict__ conv_w,
    const float* __restrict__ conv_b, const float* __restrict__ dt_bias,
    float* __restrict__ convout, float* __restrict__ dtbuf)
{
    int idx = blockIdx.x * 256 + threadIdx.x;   // over 4096*1168
    int bl = idx / 1168;
    int c  = idx - bl * 1168;
    int l  = bl & (LL - 1);
    if (c < CONVDIM) {
        const float* col = zx + (size_t)bl * NPROJ_PAD + DINNER + c;
        float acc = conv_b[c];
        #pragma unroll
        for (int i = 0; i < 4; i++) {
            int lt = l - 3 + i;
            float v = (lt >= 0) ? col[(long long)(lt - l) * NPROJ_PAD] : 0.f;
            acc = fmaf(v, conv_w[c * 4 + i], acc);
        }
        convout[(size_t)bl * CONVDIM + c] = silu_f(acc);
    } else {
        int h = c - CONVDIM;
        float v = zx[(size_t)bl * NPROJ_PAD + 2176 + h] + dt_bias[h];
        float sp = (v > 20.f) ? v : log1pf(__expf(v));
        dtbuf[(size_t)bl * NHEADS + h] = sp;
    }
}

// ----------------------- chunked SSM scan: phase 1 -------------------------
// block = (((b*16+h)*4+nq)*16+c); lane p; 64 steps from zero state.
__global__ __launch_bounds__(64) void scan_phase1(
    const float* __restrict__ convout, const float* __restrict__ dtbuf,
    const float* __restrict__ A_log, float* __restrict__ Sc,
    float* __restrict__ Ptot)
{
    int blk = blockIdx.x;
    int c   = blk & 15;
    int bhq = blk >> 4;
    int nq  = bhq & 3;
    int bh  = bhq >> 2;
    int b = bh >> 4, h = bh & 15;
    int p = threadIdx.x;
    float Ah = -__expf(A_log[h]);
    size_t base = ((size_t)b * LL + (size_t)c * CHUNK) * CONVDIM;
    const float* xb = convout + base + h * HEADDIM + p;
    const float* Bb = convout + base + DINNER + nq * 16;
    const float* db = dtbuf + ((size_t)b * LL + (size_t)c * CHUNK) * NHEADS + h;

    float s[16];
    #pragma unroll
    for (int j = 0; j < 16; j++) s[j] = 0.f;
    float dtsum = 0.f;

    float dtc = db[0], xvc = xb[0];
    float Bv[16];
    #pragma unroll
    for (int j = 0; j < 16; j++) Bv[j] = Bb[j];

    for (int t = 0; t < CHUNK; ++t) {
        float dt = dtc, xv = xvc;
        float Bl[16];
        #pragma unroll
        for (int j = 0; j < 16; j++) Bl[j] = Bv[j];
        int tn = (t < CHUNK - 1) ? t + 1 : CHUNK - 1;
        dtc = db[(size_t)tn * NHEADS];
        xvc = xb[(size_t)tn * CONVDIM];
        const float* Bt = Bb + (size_t)tn * CONVDIM;
        #pragma unroll
        for (int j = 0; j < 16; j++) Bv[j] = Bt[j];
        float dA = __expf(dt * Ah);
        dtsum += dt;
        float coef = dt * xv;
        #pragma unroll
        for (int j = 0; j < 16; j++) s[j] = fmaf(s[j], dA, coef * Bl[j]);
    }
    float* So = Sc + (size_t)blk * 1024 + p * 16;
    #pragma unroll
    for (int q = 0; q < 4; q++) {
        float4 v; v.x = s[q*4]; v.y = s[q*4+1]; v.z = s[q*4+2]; v.w = s[q*4+3];
        *reinterpret_cast<float4*>(So + q * 4) = v;
    }
    if (nq == 0 && p == 0) Ptot[bh * 16 + c] = __expf(Ah * dtsum);
}

// ----------------------- chunked SSM scan: phase 2 -------------------------
__global__ __launch_bounds__(64) void scan_combine(
    const float* __restrict__ Sc, const float* __restrict__ Ptot,
    float* __restrict__ Sinit)
{
    int blk = blockIdx.x;
    int bh = blk >> 2;
    int p = threadIdx.x;
    float carry[16];
    #pragma unroll
    for (int j = 0; j < 16; j++) carry[j] = 0.f;
    for (int c = 0; c < NCHUNK; ++c) {
        size_t row = ((size_t)blk * 16 + c) * 1024 + p * 16;
        float* o = Sinit + row;
        #pragma unroll
        for (int j = 0; j < 16; j++) o[j] = carry[j];
        float P = Ptot[bh * 16 + c];
        const float* si = Sc + row;
        #pragma unroll
        for (int j = 0; j < 16; j++) carry[j] = fmaf(carry[j], P, si[j]);
    }
}

// ----------------------- chunked SSM scan: phase 3 -------------------------
// block = (((b*16+h)*2+nh)*16+c), 64 lanes; lane p carries the 32 states of
// n-half nh. y half-sum is per-lane complete -> plain coalesced store into
// partial buffer yp (yp0/yp1 summed later by gated_rms). No cross-lane ops.
__global__ __launch_bounds__(64) void scan_phase2(
    const float* __restrict__ convout, const float* __restrict__ dtbuf,
    const float* __restrict__ A_log, const float* __restrict__ Sinit,
    float* __restrict__ yp0, float* __restrict__ yp1)
{
    int blk = blockIdx.x;
    int c   = blk & 15;
    int bhh = blk >> 4;                // (b*16+h)*2 + nh
    int nh  = bhh & 1;
    int bh  = bhh >> 1;
    int b = bh >> 4, h = bh & 15;
    int p = threadIdx.x;
    float Ah = -__expf(A_log[h]);

    size_t base = ((size_t)b * LL + (size_t)c * CHUNK) * CONVDIM;
    const float* xb = convout + base + h * HEADDIM + p;
    const float* Bb = convout + base + DINNER + nh * 32;
    const float* Cb = Bb + DSTATE;
    const float* db = dtbuf + ((size_t)b * LL + (size_t)c * CHUNK) * NHEADS + h;
    float* yb = (nh ? yp1 : yp0)
              + ((size_t)b * LL + (size_t)c * CHUNK) * DINNER + h * HEADDIM + p;

    float s[32];
    {   // states jj<16 from quarter 2*nh, jj>=16 from quarter 2*nh+1
        const float* si0 = Sinit + ((size_t)(bh * 4 + nh * 2)     * 16 + c) * 1024 + p * 16;
        const float* si1 = Sinit + ((size_t)(bh * 4 + nh * 2 + 1) * 16 + c) * 1024 + p * 16;
        #pragma unroll
        for (int j = 0; j < 16; j++) { s[j] = si0[j]; s[16 + j] = si1[j]; }
    }

    float dtc = db[0], xvc = xb[0];
    float Bv[32], Cv[32];
    #pragma unroll
    for (int j = 0; j < 32; j++) { Bv[j] = Bb[j]; Cv[j] = Cb[j]; }

    for (int t = 0; t < CHUNK; ++t) {
        float dt = dtc, xv = xvc;
        float Bl[32], Cl[32];
        #pragma unroll
        for (int j = 0; j < 32; j++) { Bl[j] = Bv[j]; Cl[j] = Cv[j]; }
        int tn = (t < CHUNK - 1) ? t + 1 : CHUNK - 1;
        dtc = db[(size_t)tn * NHEADS];
        xvc = xb[(size_t)tn * CONVDIM];
        const float* Bt = Bb + (size_t)tn * CONVDIM;
        const float* Ct = Cb + (size_t)tn * CONVDIM;
        #pragma unroll
        for (int j = 0; j < 32; j++) { Bv[j] = Bt[j]; Cv[j] = Ct[j]; }
        float dA = __expf(dt * Ah);
        float coef = dt * xv;
        float yacc = 0.f;
        #pragma unroll
        for (int j = 0; j < 32; j++) {
            s[j] = fmaf(s[j], dA, coef * Bl[j]);
            yacc = fmaf(s[j], Cl[j], yacc);
        }
        yb[(size_t)t * DINNER] = yacc;    // plain store, 64 lanes coalesced
    }
}

// ------------- gated RMSNorm (yp0+yp1+xD)*silu(z), bf16 out ----------------
__global__ __launch_bounds__(256) void gated_rms_kernel(
    const float* __restrict__ yp0, const float* __restrict__ yp1,
    const float* __restrict__ convout, const float* __restrict__ zx,
    const float* __restrict__ Dv, const float* __restrict__ norm_w,
    u16* __restrict__ gout)
{
    int bl = blockIdx.x;
    int c = threadIdx.x * 4;
    float4 y0 = *reinterpret_cast<const float4*>(yp0 + (size_t)bl * DINNER + c);
    float4 y1 = *reinterpret_cast<const float4*>(yp1 + (size_t)bl * DINNER + c);
    float4 xv = *reinterpret_cast<const float4*>(convout + (size_t)bl * CONVDIM + c);
    float4 zv = *reinterpret_cast<const float4*>(zx + (size_t)bl * NPROJ_PAD + c);
    float Dh = Dv[c >> 6];
    float g0 = (y0.x + y1.x + xv.x * Dh) * silu_f(zv.x);
    float g1 = (y0.y + y1.y + xv.y * Dh) * silu_f(zv.y);
    float g2 = (y0.z + y1.z + xv.z * Dh) * silu_f(zv.z);
    float g3 = (y0.w + y1.w + xv.w * Dh) * silu_f(zv.w);
    float tot = block_sum(g0 * g0 + g1 * g1 + g2 * g2 + g3 * g3);
    float sc = rsqrtf(tot * (1.f / DINNER) + 1e-5f);
    float4 nw = *reinterpret_cast<const float4*>(norm_w + c);
    ushort4 o;
    o.x = f2bf(g0 * sc * nw.x); o.y = f2bf(g1 * sc * nw.y);
    o.z = f2bf(g2 * sc * nw.z); o.w = f2bf(g3 * sc * nw.w);
    *reinterpret_cast<ushort4*>(gout + (size_t)bl * DINNER + c) = o;
}

// ---------------- residual + RMSNorm (no weight), f32 out ------------------
__global__ void residual_rms_kernel(
    const float* __restrict__ a, const float* __restrict__ b,
    float* __restrict__ outf, int ncols)
{
    int row = blockIdx.x;
    int c = threadIdx.x * 4;
    float4 va = *reinterpret_cast<const float4*>(a + (size_t)row * ncols + c);
    float4 vb = *reinterpret_cast<const float4*>(b + (size_t)row * ncols + c);
    float v0 = va.x + vb.x, v1 = va.y + vb.y, v2 = va.z + vb.z, v3 = va.w + vb.w;
    float tot = block_sum(v0 * v0 + v1 * v1 + v2 * v2 + v3 * v3);
    float sc = rsqrtf(tot / (float)ncols + 1e-5f);
    float4 o; o.x = v0 * sc; o.y = v1 * sc; o.z = v2 * sc; o.w = v3 * sc;
    *reinterpret_cast<float4*>(outf + (size_t)row * ncols + c) = o;
}

// ------------- transpose per batch: in (R,C) -> out (C,R), dual write ------
__global__ __launch_bounds__(256) void transpose_dual_kernel(
    const float* __restrict__ in, u16* __restrict__ outb,
    float* __restrict__ outf, int R, int C)
{
    __shared__ float tile[32][33];
    int b = blockIdx.z;
    int c0 = blockIdx.x * 32, r0 = blockIdx.y * 32;
    const float* ip = in + (size_t)b * R * C;
    for (int i = threadIdx.y; i < 32; i += 8)
        tile[i][threadIdx.x] = ip[(size_t)(r0 + i) * C + c0 + threadIdx.x];
    __syncthreads();
    size_t ob = (size_t)b * R * C;
    for (int i = threadIdx.y; i < 32; i += 8) {
        float v = tile[threadIdx.x][i];
        size_t oi = ob + (size_t)(c0 + i) * R + r0 + threadIdx.x;
        outf[oi] = v;
        outb[oi] = f2bf(v);
    }
}

// ------------------------------ SwiGLU -------------------------------------
__global__ __launch_bounds__(256) void swiglu_kernel(
    const float* __restrict__ t, u16* __restrict__ act, int rows, int inter)
{
    int idx = blockIdx.x * 256 + threadIdx.x;
    if (idx >= rows * inter) return;
    int r = idx / inter, c = idx - r * inter;
    float g = t[(size_t)r * 2 * inter + c];
    float u = t[(size_t)r * 2 * inter + inter + c];
    act[idx] = f2bf(silu_f(g) * u);
}

// ---------------------------------------------------------------------------
extern "C" void kernel_launch(void* const* d_in, const int* in_sizes, int n_in,
                              void* d_out, int out_size, void* d_ws, size_t ws_size,
                              hipStream_t stream)
{
    const float* hid      = (const float*)d_in[0];
    const float* in_proj  = (const float*)d_in[1];
    const float* conv_w   = (const float*)d_in[2];
    const float* conv_b   = (const float*)d_in[3];
    const float* dt_bias  = (const float*)d_in[4];
    const float* A_log    = (const float*)d_in[5];
    const float* Dv       = (const float*)d_in[6];
    const float* norm_w   = (const float*)d_in[7];
    const float* out_proj = (const float*)d_in[8];
    const float* gu_t     = (const float*)d_in[9];
    const float* down_t   = (const float*)d_in[10];
    const float* gu_m     = (const float*)d_in[11];
    const float* down_m   = (const float*)d_in[12];
    float* outp = (float*)d_out;

    char* ws = (char*)d_ws;
    u16* bf        = (u16*)ws;
    u16* hid_bf    = bf;
    u16* w_inproj  = bf + HID_E;
    u16* w_outproj = w_inproj + INPROJ_P_E;
    u16* w_gut     = w_outproj + OUTPROJ_E;
    u16* w_downt   = w_gut + GUT_E;
    u16* w_gum     = w_downt + DOWNT_E;
    u16* w_downm   = w_gum + GUM_E;
    size_t o = (size_t)(CONV_TOT_E * 2);
    auto alloc = [&](size_t bytes) { size_t r = o; o = (o + bytes + 255) & ~(size_t)255; return r; };
    size_t dt_off  = alloc(4096 * 16 * 4);
    size_t g_off   = alloc((size_t)4096 * 1024 * 2);
    size_t out2_off= alloc((size_t)4096 * 512 * 4);
    size_t h1_off  = alloc((size_t)4096 * 512 * 4);
    size_t xtb_off = alloc((size_t)2048 * 1024 * 2);
    size_t xtf_off = alloc((size_t)2048 * 1024 * 4);
    size_t act1_off= alloc((size_t)2048 * 2816 * 2);
    size_t t2_off  = alloc((size_t)2048 * 1024 * 4);
    size_t x2_off  = alloc((size_t)2048 * 1024 * 4);
    size_t h2b_off = alloc((size_t)4096 * 512 * 2);
    size_t h2f_off = alloc((size_t)4096 * 512 * 4);
    size_t act2_off= alloc((size_t)4096 * 1536 * 2);
    size_t t4_off  = alloc((size_t)4096 * 512 * 4);
    size_t Sc_off  = alloc((size_t)4096 * 1024 * 4);   // chunk states; reused as yp1
    size_t Si_off  = alloc((size_t)4096 * 1024 * 4);
    size_t Pt_off  = alloc(1024 * 4);
    // overlay region: {zxbcdt, convout, ybuf} live until gated_rms; t1/t3 after
    size_t R_off   = o;
    size_t zx_off  = R_off;
    size_t cv_off  = zx_off + (size_t)4096 * NPROJ_PAD * 4;
    size_t y_off   = cv_off + (size_t)4096 * CONVDIM * 4;
    size_t t1_off  = R_off;
    size_t t3_off  = R_off;

    float* zx      = (float*)(ws + zx_off);
    float* convout = (float*)(ws + cv_off);
    float* ybuf    = (float*)(ws + y_off);           // yp0
    float* dtbuf   = (float*)(ws + dt_off);
    u16*   g_bf    = (u16*)(ws + g_off);
    float* out2    = (float*)(ws + out2_off);
    float* h1      = (float*)(ws + h1_off);
    u16*   xt_bf   = (u16*)(ws + xtb_off);
    float* xt_f    = (float*)(ws + xtf_off);
    float* t1      = (float*)(ws + t1_off);
    u16*   act1    = (u16*)(ws + act1_off);
    float* t2      = (float*)(ws + t2_off);
    float* x2      = (float*)(ws + x2_off);
    u16*   h2_bf   = (u16*)(ws + h2b_off);
    float* h2_f    = (float*)(ws + h2f_off);
    float* t3      = (float*)(ws + t3_off);
    u16*   act2    = (u16*)(ws + act2_off);
    float* t4      = (float*)(ws + t4_off);
    float* Sc      = (float*)(ws + Sc_off);          // yp1 after scan_combine
    float* Sinit   = (float*)(ws + Si_off);
    float* Ptot    = (float*)(ws + Pt_off);

    // 0) zero split-K GEMM outputs (atomic accumulation)
    hipMemsetAsync(out2, 0, (size_t)4096 * 512 * 4, stream);
    hipMemsetAsync(t2,   0, (size_t)2048 * 1024 * 4, stream);
    hipMemsetAsync(t4,   0, (size_t)4096 * 512 * 4, stream);

    // 1) convert weights + hidden to bf16
    convert_all_kernel<<<14464, 256, 0, stream>>>(
        hid, in_proj, out_proj, gu_t, down_t, gu_m, down_m, bf);

    // 2) zxbcdt = hidden @ in_proj^T  (576 blocks)
    gemm_bt<<<dim3(NPROJ_PAD / 128, 4096 / 128), 256, 0, stream>>>(
        hid_bf, w_inproj, zx, 4096, NPROJ_PAD, 512);

    // 3) conv + dt
    conv_dt_kernel<<<18688, 256, 0, stream>>>(zx, conv_w, conv_b, dt_bias, convout, dtbuf);

    // 4) chunked SSM scan (phase2: halves; yp0=ybuf, yp1=Sc reuse)
    scan_phase1<<<4096, 64, 0, stream>>>(convout, dtbuf, A_log, Sc, Ptot);
    scan_combine<<<256, 64, 0, stream>>>(Sc, Ptot, Sinit);
    scan_phase2<<<2048, 64, 0, stream>>>(convout, dtbuf, A_log, Sinit, ybuf, Sc);

    // 5) gated RMSNorm -> bf16
    gated_rms_kernel<<<4096, 256, 0, stream>>>(ybuf, Sc, convout, zx, Dv, norm_w, g_bf);

    // 6) out_proj GEMM, split-K x4 (512 blocks)
    gemm_bt_sk<<<dim3(512 / 128, 4096 / 128, 4), 256, 0, stream>>>(
        g_bf, w_outproj, out2, 4096, 512, 1024, 256);

    // 7) h1 = rms(hidden + out2)
    residual_rms_kernel<<<4096, 128, 0, stream>>>(hid, out2, h1, 512);

    // 8) transpose (B,1024,512) -> (B,512,1024)
    transpose_dual_kernel<<<dim3(16, 32, 4), dim3(32, 8), 0, stream>>>(h1, xt_bf, xt_f, 1024, 512);

    // 9) token MLP: t1 = xt @ gu_t^T (704 blocks)
    gemm_bt<<<dim3(5632 / 128, 2048 / 128), 256, 0, stream>>>(xt_bf, w_gut, t1, 2048, 5632, 1024);

    // 10) swiglu -> act1 bf16
    swiglu_kernel<<<22528, 256, 0, stream>>>(t1, act1, 2048, 2816);

    // 11) t2 = act1 @ down_t^T, split-K x4 (512 blocks)
    gemm_bt_sk<<<dim3(1024 / 128, 2048 / 128, 4), 256, 0, stream>>>(
        act1, w_downt, t2, 2048, 1024, 2816, 704);

    // 12) x2 = rms(xt_f + t2)
    residual_rms_kernel<<<2048, 256, 0, stream>>>(xt_f, t2, x2, 1024);

    // 13) transpose back (B,512,1024) -> (B,1024,512)
    transpose_dual_kernel<<<dim3(32, 16, 4), dim3(32, 8), 0, stream>>>(x2, h2_bf, h2_f, 512, 1024);

    // 14) channel MLP: t3 = h2 @ gu_m^T (768 blocks)
    gemm_bt<<<dim3(3072 / 128, 4096 / 128), 256, 0, stream>>>(h2_bf, w_gum, t3, 4096, 3072, 512);

    // 15) swiglu -> act2 bf16
    swiglu_kernel<<<24576, 256, 0, stream>>>(t3, act2, 4096, 1536);

    // 16) t4 = act2 @ down_m^T, split-K x4 (512 blocks)
    gemm_bt_sk<<<dim3(512 / 128, 4096 / 128, 4), 256, 0, stream>>>(
        act2, w_downm, t4, 4096, 512, 1536, 384);

    // 17) out = rms(h2_f + t4)
    residual_rms_kernel<<<4096, 128, 0, stream>>>(h2_f, t4, outp, 512);
}

// Round 7
// 486.878 us; speedup vs baseline: 1.1367x; 1.0496x over previous
//
#include <hip/hip_runtime.h>

// ---------------------------------------------------------------------------
// Mamba2 hybrid block. GEMMs: bf16 MFMA 16x16x32, f32 accumulate, m97-style
// global_load_lds(16B) staging with XOR bank swizzle; small-N GEMMs use
// split-K x4 with f32 atomicAdd epilogue. Scan: 3-phase chunked, CHUNK=32;
// B/C/dt staged in LDS per chunk (bulk coalesced load, wave-uniform ds_read
// in the loop); y per-lane complete (32 states/lane in phase2) -> plain
// stores to two partial buffers summed by gated_rms.
// Lessons: R4 ds_add same-address serializes; R5 per-step shfl serializes on
// LDS pipe; R6 per-step global B/C loads are latency-bound at low TLP.
// ---------------------------------------------------------------------------

#define BB 4
#define LL 1024
#define DMODEL 512
#define DINNER 1024
#define NHEADS 16
#define HEADDIM 64
#define DSTATE 64
#define CONVDIM 1152        // DINNER + 2*DSTATE
#define NPROJ 2192          // D_IN_PROJ
#define NPROJ_PAD 2304      // padded to multiple of 128
#define INTER_T 2816
#define INTER_M 1536
#define NCHUNK 32
#define CHUNK 32

typedef __bf16 bf16x8 __attribute__((ext_vector_type(8)));
typedef float  f32x4  __attribute__((ext_vector_type(4)));
typedef unsigned short u16;
typedef unsigned int   u32;

__device__ __forceinline__ u16 f2bf(float x) {
    union { float f; u32 u; } v; v.f = x;
    u32 u = v.u;
    return (u16)((u + 0x7fffu + ((u >> 16) & 1u)) >> 16);
}
__device__ __forceinline__ float silu_f(float x) {
    return x / (1.f + __expf(-x));
}

// async global->LDS, 16B per lane; LDS dest is wave-uniform base + lane*16
__device__ __forceinline__ void gld_lds16(const u16* g, u16* l) {
    __builtin_amdgcn_global_load_lds(
        (const __attribute__((address_space(1))) unsigned int*)g,
        (__attribute__((address_space(3))) unsigned int*)l, 16, 0, 0);
}

// --------------------------- block-wide sum --------------------------------
__device__ __forceinline__ float block_sum(float v) {
    #pragma unroll
    for (int off = 32; off > 0; off >>= 1) v += __shfl_xor(v, off, 64);
    __shared__ float red[4];
    int w = threadIdx.x >> 6;
    int nwv = blockDim.x >> 6;
    if ((threadIdx.x & 63) == 0) red[w] = v;
    __syncthreads();
    float tot = red[0];
    for (int i = 1; i < nwv; i++) tot += red[i];
    return tot;
}

// --------------------- f32 -> bf16 convert (all weights + hidden) ----------
#define HID_E      2097152LL   // 4096*512
#define INPROJ_P_E 1179648LL   // 2304*512
#define INPROJ_S_E 1122304LL   // 2192*512
#define OUTPROJ_E   524288LL   // 512*1024
#define GUT_E      5767168LL   // 5632*1024
#define DOWNT_E    2883584LL   // 1024*2816
#define GUM_E      1572864LL   // 3072*512
#define DOWNM_E     786432LL   // 512*1536
#define CONV_TOT_E 14811136LL

__global__ __launch_bounds__(256) void convert_all_kernel(
    const float* __restrict__ s_hid, const float* __restrict__ s_inproj,
    const float* __restrict__ s_outproj, const float* __restrict__ s_gut,
    const float* __restrict__ s_downt, const float* __restrict__ s_gum,
    const float* __restrict__ s_downm, u16* __restrict__ dst)
{
    long long idx = (long long)blockIdx.x * 256 + threadIdx.x;
    long long e = idx * 4;
    if (e >= CONV_TOT_E) return;
    const float* src; long long off, nsrc;
    long long c0 = HID_E;
    long long c1 = c0 + INPROJ_P_E;
    long long c2 = c1 + OUTPROJ_E;
    long long c3 = c2 + GUT_E;
    long long c4 = c3 + DOWNT_E;
    long long c5 = c4 + GUM_E;
    if      (e < c0) { src = s_hid;     off = e;      nsrc = HID_E; }
    else if (e < c1) { src = s_inproj;  off = e - c0; nsrc = INPROJ_S_E; }
    else if (e < c2) { src = s_outproj; off = e - c1; nsrc = OUTPROJ_E; }
    else if (e < c3) { src = s_gut;     off = e - c2; nsrc = GUT_E; }
    else if (e < c4) { src = s_downt;   off = e - c3; nsrc = DOWNT_E; }
    else if (e < c5) { src = s_gum;     off = e - c4; nsrc = GUM_E; }
    else             { src = s_downm;   off = e - c5; nsrc = DOWNM_E; }
    ushort4 r;
    if (off < nsrc) {
        float4 v = *reinterpret_cast<const float4*>(src + off);
        r.x = f2bf(v.x); r.y = f2bf(v.y); r.z = f2bf(v.z); r.w = f2bf(v.w);
    } else {
        r.x = 0; r.y = 0; r.z = 0; r.w = 0;
    }
    *reinterpret_cast<ushort4*>(dst + e) = r;
}

// ----------------------------- bf16 MFMA GEMM ------------------------------
// C[M,N] = A[M,K] * W[N,K]^T. 128x128 tile, 4 waves of 64x64 (4x4 MFMAs).
// global_load_lds staging (no pad; XOR chunk swizzle vs bank conflicts).
template<bool ATOMIC>
__device__ __forceinline__ void gemm_bt_body(
    const u16* __restrict__ A, const u16* __restrict__ W,
    float* __restrict__ C, int M, int N, int K, int kBase, int kLen)
{
    __shared__ u16 As[128 * 32];
    __shared__ u16 Bs[128 * 32];
    int tid = threadIdx.x;
    int m0 = blockIdx.y * 128, n0 = blockIdx.x * 128;
    int wave = tid >> 6, lane = tid & 63;
    int wm = (wave >> 1) * 64, wn = (wave & 1) * 64;
    int lrow = lane & 15;
    int kq = lane >> 4;
    int kx = (lrow & 3) ^ ((lrow >> 2) & 3);
    int ko = (kq ^ kx) * 8;           // swizzled LDS chunk offset for frags

    int rL = lane >> 2, cL = lane & 3;
    int cG = cL ^ ((rL & 3) ^ ((rL >> 2) & 3));
    int R0 = wave * 32 + rL;
    int R1 = R0 + 16;
    const u16* gA0 = A + (size_t)(m0 + R0) * K + kBase + cG * 8;
    const u16* gA1 = A + (size_t)(m0 + R1) * K + kBase + cG * 8;
    const u16* gB0 = W + (size_t)(n0 + R0) * K + kBase + cG * 8;
    const u16* gB1 = W + (size_t)(n0 + R1) * K + kBase + cG * 8;
    u16* lA0 = &As[(wave * 32) * 32];
    u16* lA1 = &As[(wave * 32 + 16) * 32];
    u16* lB0 = &Bs[(wave * 32) * 32];
    u16* lB1 = &Bs[(wave * 32 + 16) * 32];

    f32x4 acc[4][4];
    #pragma unroll
    for (int i = 0; i < 4; i++)
        #pragma unroll
        for (int j = 0; j < 4; j++) {
            acc[i][j][0] = 0.f; acc[i][j][1] = 0.f;
            acc[i][j][2] = 0.f; acc[i][j][3] = 0.f;
        }

    for (int kt = 0; kt < kLen; kt += 32) {
        __syncthreads();
        gld_lds16(gA0 + kt, lA0);
        gld_lds16(gA1 + kt, lA1);
        gld_lds16(gB0 + kt, lB0);
        gld_lds16(gB1 + kt, lB1);
        __syncthreads();
        bf16x8 af[4], bfr[4];
        #pragma unroll
        for (int i = 0; i < 4; i++) {
            af[i]  = *reinterpret_cast<const bf16x8*>(&As[(wm + i * 16 + lrow) * 32 + ko]);
            bfr[i] = *reinterpret_cast<const bf16x8*>(&Bs[(wn + i * 16 + lrow) * 32 + ko]);
        }
        #pragma unroll
        for (int i = 0; i < 4; i++)
            #pragma unroll
            for (int j = 0; j < 4; j++)
                acc[i][j] = __builtin_amdgcn_mfma_f32_16x16x32_bf16(af[i], bfr[j], acc[i][j], 0, 0, 0);
    }

    // C/D layout: col = lane&15, row = (lane>>4)*4 + reg
    int rbase = m0 + wm + kq * 4;
    int cbase = n0 + wn + lrow;
    #pragma unroll
    for (int i = 0; i < 4; i++)
        #pragma unroll
        for (int j = 0; j < 4; j++)
            #pragma unroll
            for (int r = 0; r < 4; r++) {
                float* p = &C[(size_t)(rbase + i * 16 + r) * N + cbase + j * 16];
                if (ATOMIC) atomicAdd(p, acc[i][j][r]);
                else        *p = acc[i][j][r];
            }
}

__global__ __launch_bounds__(256) void gemm_bt(
    const u16* __restrict__ A, const u16* __restrict__ W,
    float* __restrict__ C, int M, int N, int K)
{
    gemm_bt_body<false>(A, W, C, M, N, K, 0, K);
}

__global__ __launch_bounds__(256) void gemm_bt_sk(
    const u16* __restrict__ A, const u16* __restrict__ W,
    float* __restrict__ C, int M, int N, int K, int kLen)
{
    gemm_bt_body<true>(A, W, C, M, N, K, blockIdx.z * kLen, kLen);
}

// ----------------- conv (depthwise, causal, width 4) + dt ------------------
__global__ __launch_bounds__(256) void conv_dt_kernel(
    const float* __restrict__ zx, const float* __restrict__ conv_w,
    const float* __restrict__ conv_b, const float* __restrict__ dt_bias,
    float* __restrict__ convout, float* __restrict__ dtbuf)
{
    int idx = blockIdx.x * 256 + threadIdx.x;   // over 4096*1168
    int bl = idx / 1168;
    int c  = idx - bl * 1168;
    int l  = bl & (LL - 1);
    if (c < CONVDIM) {
        const float* col = zx + (size_t)bl * NPROJ_PAD + DINNER + c;
        float acc = conv_b[c];
        #pragma unroll
        for (int i = 0; i < 4; i++) {
            int lt = l - 3 + i;
            float v = (lt >= 0) ? col[(long long)(lt - l) * NPROJ_PAD] : 0.f;
            acc = fmaf(v, conv_w[c * 4 + i], acc);
        }
        convout[(size_t)bl * CONVDIM + c] = silu_f(acc);
    } else {
        int h = c - CONVDIM;
        float v = zx[(size_t)bl * NPROJ_PAD + 2176 + h] + dt_bias[h];
        float sp = (v > 20.f) ? v : log1pf(__expf(v));
        dtbuf[(size_t)bl * NHEADS + h] = sp;
    }
}

// ----------------------- chunked SSM scan: phase 1 -------------------------
// block = (b*16+h)*32 + c, 256 thr; wave = nq (16 states/lane); B/dt staged
// in LDS once per chunk. 32 steps from zero state -> Sc, Ptot.
__global__ __launch_bounds__(256) void scan_phase1(
    const float* __restrict__ convout, const float* __restrict__ dtbuf,
    const float* __restrict__ A_log, float* __restrict__ Sc,
    float* __restrict__ Ptot)
{
    __shared__ float Blds[CHUNK * 64];   // 8 KB
    __shared__ float dtl[CHUNK];
    int blk = blockIdx.x;
    int c   = blk & 31;
    int bh  = blk >> 5;
    int b = bh >> 4, h = bh & 15;
    int nq = threadIdx.x >> 6;
    int p  = threadIdx.x & 63;
    size_t base = ((size_t)b * LL + (size_t)c * CHUNK) * CONVDIM;

    const float* Bsrc = convout + base + DINNER;
    #pragma unroll
    for (int i = threadIdx.x; i < CHUNK * 16; i += 256) {   // 512 float4s
        int t = i >> 4, q = i & 15;
        *reinterpret_cast<float4*>(&Blds[t * 64 + q * 4]) =
            *reinterpret_cast<const float4*>(&Bsrc[(size_t)t * CONVDIM + q * 4]);
    }
    const float* db = dtbuf + ((size_t)b * LL + (size_t)c * CHUNK) * NHEADS + h;
    if (threadIdx.x < CHUNK) dtl[threadIdx.x] = db[(size_t)threadIdx.x * NHEADS];
    __syncthreads();

    float Ah = -__expf(A_log[h]);
    const float* xb = convout + base + h * HEADDIM + p;

    float s[16];
    #pragma unroll
    for (int j = 0; j < 16; j++) s[j] = 0.f;
    float dtsum = 0.f;

    float dtc = dtl[0], xvc = xb[0];
    float Bv[16];
    #pragma unroll
    for (int j = 0; j < 16; j++) Bv[j] = Blds[nq * 16 + j];

    for (int t = 0; t < CHUNK; ++t) {
        float dt = dtc, xv = xvc;
        float Bl[16];
        #pragma unroll
        for (int j = 0; j < 16; j++) Bl[j] = Bv[j];
        int tn = (t < CHUNK - 1) ? t + 1 : CHUNK - 1;
        dtc = dtl[tn];
        xvc = xb[(size_t)tn * CONVDIM];
        #pragma unroll
        for (int j = 0; j < 16; j++) Bv[j] = Blds[tn * 64 + nq * 16 + j];
        float dA = __expf(dt * Ah);
        dtsum += dt;
        float coef = dt * xv;
        #pragma unroll
        for (int j = 0; j < 16; j++) s[j] = fmaf(s[j], dA, coef * Bl[j]);
    }
    float* So = Sc + ((size_t)(bh * 4 + nq) * NCHUNK + c) * 1024 + p * 16;
    #pragma unroll
    for (int q = 0; q < 4; q++) {
        float4 v; v.x = s[q*4]; v.y = s[q*4+1]; v.z = s[q*4+2]; v.w = s[q*4+3];
        *reinterpret_cast<float4*>(So + q * 4) = v;
    }
    if (nq == 0 && p == 0) Ptot[bh * NCHUNK + c] = __expf(Ah * dtsum);
}

// ----------------------- chunked SSM scan: phase 2 -------------------------
// block = (b*16+h)*4 + nq (256 blocks); sequential carry over 32 chunks.
__global__ __launch_bounds__(64) void scan_combine(
    const float* __restrict__ Sc, const float* __restrict__ Ptot,
    float* __restrict__ Sinit)
{
    int blk = blockIdx.x;
    int bh = blk >> 2;
    int p = threadIdx.x;
    float carry[16];
    #pragma unroll
    for (int j = 0; j < 16; j++) carry[j] = 0.f;
    for (int c = 0; c < NCHUNK; ++c) {
        size_t row = ((size_t)blk * NCHUNK + c) * 1024 + p * 16;
        float* o = Sinit + row;
        #pragma unroll
        for (int j = 0; j < 16; j++) o[j] = carry[j];
        float P = Ptot[bh * NCHUNK + c];
        const float* si = Sc + row;
        #pragma unroll
        for (int j = 0; j < 16; j++) carry[j] = fmaf(carry[j], P, si[j]);
    }
}

// ----------------------- chunked SSM scan: phase 3 -------------------------
// block = (b*16+h)*32 + c, 128 thr; wave = nh (32 states/lane). Full B+C tile
// (32 steps x 128 floats) + dt staged in LDS; y per-lane complete -> plain
// coalesced stores into partial buffers yp0/yp1 (summed by gated_rms).
__global__ __launch_bounds__(128) void scan_phase2(
    const float* __restrict__ convout, const float* __restrict__ dtbuf,
    const float* __restrict__ A_log, const float* __restrict__ Sinit,
    float* __restrict__ yp0, float* __restrict__ yp1)
{
    __shared__ float BClds[CHUNK * 128];   // 16 KB
    __shared__ float dtl[CHUNK];
    int blk = blockIdx.x;
    int c   = blk & 31;
    int bh  = blk >> 5;
    int b = bh >> 4, h = bh & 15;
    int nh = threadIdx.x >> 6;
    int p  = threadIdx.x & 63;
    size_t base = ((size_t)b * LL + (size_t)c * CHUNK) * CONVDIM;

    const float* BCsrc = convout + base + DINNER;
    #pragma unroll
    for (int i = threadIdx.x; i < CHUNK * 32; i += 128) {   // 1024 float4s
        int t = i >> 5, q = i & 31;
        *reinterpret_cast<float4*>(&BClds[t * 128 + q * 4]) =
            *reinterpret_cast<const float4*>(&BCsrc[(size_t)t * CONVDIM + q * 4]);
    }
    const float* db = dtbuf + ((size_t)b * LL + (size_t)c * CHUNK) * NHEADS + h;
    if (threadIdx.x < CHUNK) dtl[threadIdx.x] = db[(size_t)threadIdx.x * NHEADS];
    __syncthreads();

    float Ah = -__expf(A_log[h]);
    const float* xb = convout + base + h * HEADDIM + p;
    float* yb = (nh ? yp1 : yp0)
              + ((size_t)b * LL + (size_t)c * CHUNK) * DINNER + h * HEADDIM + p;

    float s[32];
    {   // states j<16 from quarter 2*nh, j>=16 from quarter 2*nh+1
        const float* si0 = Sinit + ((size_t)(bh * 4 + nh * 2)     * NCHUNK + c) * 1024 + p * 16;
        const float* si1 = Sinit + ((size_t)(bh * 4 + nh * 2 + 1) * NCHUNK + c) * 1024 + p * 16;
        #pragma unroll
        for (int j = 0; j < 16; j++) { s[j] = si0[j]; s[16 + j] = si1[j]; }
    }

    float dtc = dtl[0], xvc = xb[0];
    float Bv[32], Cv[32];
    #pragma unroll
    for (int j = 0; j < 32; j++) {
        Bv[j] = BClds[nh * 32 + j];
        Cv[j] = BClds[64 + nh * 32 + j];
    }

    for (int t = 0; t < CHUNK; ++t) {
        float dt = dtc, xv = xvc;
        float Bl[32], Cl[32];
        #pragma unroll
        for (int j = 0; j < 32; j++) { Bl[j] = Bv[j]; Cl[j] = Cv[j]; }
        int tn = (t < CHUNK - 1) ? t + 1 : CHUNK - 1;
        dtc = dtl[tn];
        xvc = xb[(size_t)tn * CONVDIM];
        #pragma unroll
        for (int j = 0; j < 32; j++) {
            Bv[j] = BClds[tn * 128 + nh * 32 + j];
            Cv[j] = BClds[tn * 128 + 64 + nh * 32 + j];
        }
        float dA = __expf(dt * Ah);
        float coef = dt * xv;
        float yacc = 0.f;
        #pragma unroll
        for (int j = 0; j < 32; j++) {
            s[j] = fmaf(s[j], dA, coef * Bl[j]);
            yacc = fmaf(s[j], Cl[j], yacc);
        }
        yb[(size_t)t * DINNER] = yacc;    // plain store, 64 lanes coalesced
    }
}

// ------------- gated RMSNorm (yp0+yp1+xD)*silu(z), bf16 out ----------------
__global__ __launch_bounds__(256) void gated_rms_kernel(
    const float* __restrict__ yp0, const float* __restrict__ yp1,
    const float* __restrict__ convout, const float* __restrict__ zx,
    const float* __restrict__ Dv, const float* __restrict__ norm_w,
    u16* __restrict__ gout)
{
    int bl = blockIdx.x;
    int c = threadIdx.x * 4;
    float4 y0 = *reinterpret_cast<const float4*>(yp0 + (size_t)bl * DINNER + c);
    float4 y1 = *reinterpret_cast<const float4*>(yp1 + (size_t)bl * DINNER + c);
    float4 xv = *reinterpret_cast<const float4*>(convout + (size_t)bl * CONVDIM + c);
    float4 zv = *reinterpret_cast<const float4*>(zx + (size_t)bl * NPROJ_PAD + c);
    float Dh = Dv[c >> 6];
    float g0 = (y0.x + y1.x + xv.x * Dh) * silu_f(zv.x);
    float g1 = (y0.y + y1.y + xv.y * Dh) * silu_f(zv.y);
    float g2 = (y0.z + y1.z + xv.z * Dh) * silu_f(zv.z);
    float g3 = (y0.w + y1.w + xv.w * Dh) * silu_f(zv.w);
    float tot = block_sum(g0 * g0 + g1 * g1 + g2 * g2 + g3 * g3);
    float sc = rsqrtf(tot * (1.f / DINNER) + 1e-5f);
    float4 nw = *reinterpret_cast<const float4*>(norm_w + c);
    ushort4 o;
    o.x = f2bf(g0 * sc * nw.x); o.y = f2bf(g1 * sc * nw.y);
    o.z = f2bf(g2 * sc * nw.z); o.w = f2bf(g3 * sc * nw.w);
    *reinterpret_cast<ushort4*>(gout + (size_t)bl * DINNER + c) = o;
}

// ---------------- residual + RMSNorm (no weight), f32 out ------------------
__global__ void residual_rms_kernel(
    const float* __restrict__ a, const float* __restrict__ b,
    float* __restrict__ outf, int ncols)
{
    int row = blockIdx.x;
    int c = threadIdx.x * 4;
    float4 va = *reinterpret_cast<const float4*>(a + (size_t)row * ncols + c);
    float4 vb = *reinterpret_cast<const float4*>(b + (size_t)row * ncols + c);
    float v0 = va.x + vb.x, v1 = va.y + vb.y, v2 = va.z + vb.z, v3 = va.w + vb.w;
    float tot = block_sum(v0 * v0 + v1 * v1 + v2 * v2 + v3 * v3);
    float sc = rsqrtf(tot / (float)ncols + 1e-5f);
    float4 o; o.x = v0 * sc; o.y = v1 * sc; o.z = v2 * sc; o.w = v3 * sc;
    *reinterpret_cast<float4*>(outf + (size_t)row * ncols + c) = o;
}

// ------------- transpose per batch: in (R,C) -> out (C,R), dual write ------
__global__ __launch_bounds__(256) void transpose_dual_kernel(
    const float* __restrict__ in, u16* __restrict__ outb,
    float* __restrict__ outf, int R, int C)
{
    __shared__ float tile[32][33];
    int b = blockIdx.z;
    int c0 = blockIdx.x * 32, r0 = blockIdx.y * 32;
    const float* ip = in + (size_t)b * R * C;
    for (int i = threadIdx.y; i < 32; i += 8)
        tile[i][threadIdx.x] = ip[(size_t)(r0 + i) * C + c0 + threadIdx.x];
    __syncthreads();
    size_t ob = (size_t)b * R * C;
    for (int i = threadIdx.y; i < 32; i += 8) {
        float v = tile[threadIdx.x][i];
        size_t oi = ob + (size_t)(c0 + i) * R + r0 + threadIdx.x;
        outf[oi] = v;
        outb[oi] = f2bf(v);
    }
}

// ------------------------------ SwiGLU -------------------------------------
__global__ __launch_bounds__(256) void swiglu_kernel(
    const float* __restrict__ t, u16* __restrict__ act, int rows, int inter)
{
    int idx = blockIdx.x * 256 + threadIdx.x;
    if (idx >= rows * inter) return;
    int r = idx / inter, c = idx - r * inter;
    float g = t[(size_t)r * 2 * inter + c];
    float u = t[(size_t)r * 2 * inter + inter + c];
    act[idx] = f2bf(silu_f(g) * u);
}

// ---------------------------------------------------------------------------
extern "C" void kernel_launch(void* const* d_in, const int* in_sizes, int n_in,
                              void* d_out, int out_size, void* d_ws, size_t ws_size,
                              hipStream_t stream)
{
    const float* hid      = (const float*)d_in[0];
    const float* in_proj  = (const float*)d_in[1];
    const float* conv_w   = (const float*)d_in[2];
    const float* conv_b   = (const float*)d_in[3];
    const float* dt_bias  = (const float*)d_in[4];
    const float* A_log    = (const float*)d_in[5];
    const float* Dv       = (const float*)d_in[6];
    const float* norm_w   = (const float*)d_in[7];
    const float* out_proj = (const float*)d_in[8];
    const float* gu_t     = (const float*)d_in[9];
    const float* down_t   = (const float*)d_in[10];
    const float* gu_m     = (const float*)d_in[11];
    const float* down_m   = (const float*)d_in[12];
    float* outp = (float*)d_out;

    char* ws = (char*)d_ws;
    u16* bf        = (u16*)ws;
    u16* hid_bf    = bf;
    u16* w_inproj  = bf + HID_E;
    u16* w_outproj = w_inproj + INPROJ_P_E;
    u16* w_gut     = w_outproj + OUTPROJ_E;
    u16* w_downt   = w_gut + GUT_E;
    u16* w_gum     = w_downt + DOWNT_E;
    u16* w_downm   = w_gum + GUM_E;
    size_t o = (size_t)(CONV_TOT_E * 2);
    auto alloc = [&](size_t bytes) { size_t r = o; o = (o + bytes + 255) & ~(size_t)255; return r; };
    size_t dt_off  = alloc(4096 * 16 * 4);
    size_t g_off   = alloc((size_t)4096 * 1024 * 2);
    size_t out2_off= alloc((size_t)4096 * 512 * 4);
    size_t h1_off  = alloc((size_t)4096 * 512 * 4);
    size_t Pt_off  = alloc(2048 * 4);
    // ---- MLP region (live step 8+); Sc/Sinit OVERLAY it (live steps 4-5) ----
    size_t xtb_off = alloc((size_t)2048 * 1024 * 2);
    size_t xtf_off = alloc((size_t)2048 * 1024 * 4);
    size_t act1_off= alloc((size_t)2048 * 2816 * 2);
    size_t t2_off  = alloc((size_t)2048 * 1024 * 4);
    size_t x2_off  = alloc((size_t)2048 * 1024 * 4);
    size_t h2b_off = alloc((size_t)4096 * 512 * 2);
    size_t h2f_off = alloc((size_t)4096 * 512 * 4);
    size_t act2_off= alloc((size_t)4096 * 1536 * 2);
    size_t t4_off  = alloc((size_t)4096 * 512 * 4);
    size_t Sc_off  = xtb_off;                          // 33.55 MB (8192*1024*4)
    size_t Si_off  = xtb_off + (size_t)8192 * 1024 * 4;// 33.55 MB; ends < t4 end
    // overlay region: {zxbcdt, convout, yp0} live until gated_rms; t1/t3 after
    size_t R_off   = o;
    size_t zx_off  = R_off;
    size_t cv_off  = zx_off + (size_t)4096 * NPROJ_PAD * 4;
    size_t y_off   = cv_off + (size_t)4096 * CONVDIM * 4;
    size_t t1_off  = R_off;
    size_t t3_off  = R_off;

    float* zx      = (float*)(ws + zx_off);
    float* convout = (float*)(ws + cv_off);
    float* ybuf    = (float*)(ws + y_off);           // yp0
    float* dtbuf   = (float*)(ws + dt_off);
    u16*   g_bf    = (u16*)(ws + g_off);
    float* out2    = (float*)(ws + out2_off);
    float* h1      = (float*)(ws + h1_off);
    u16*   xt_bf   = (u16*)(ws + xtb_off);
    float* xt_f    = (float*)(ws + xtf_off);
    float* t1      = (float*)(ws + t1_off);
    u16*   act1    = (u16*)(ws + act1_off);
    float* t2      = (float*)(ws + t2_off);
    float* x2      = (float*)(ws + x2_off);
    u16*   h2_bf   = (u16*)(ws + h2b_off);
    float* h2_f    = (float*)(ws + h2f_off);
    float* t3      = (float*)(ws + t3_off);
    u16*   act2    = (u16*)(ws + act2_off);
    float* t4      = (float*)(ws + t4_off);
    float* Sc      = (float*)(ws + Sc_off);          // yp1 after scan_combine
    float* Sinit   = (float*)(ws + Si_off);
    float* Ptot    = (float*)(ws + Pt_off);

    // 0) zero out_proj split-K output (not overlaid; t2/t4 zeroed later)
    hipMemsetAsync(out2, 0, (size_t)4096 * 512 * 4, stream);

    // 1) convert weights + hidden to bf16
    convert_all_kernel<<<14464, 256, 0, stream>>>(
        hid, in_proj, out_proj, gu_t, down_t, gu_m, down_m, bf);

    // 2) zxbcdt = hidden @ in_proj^T  (576 blocks)
    gemm_bt<<<dim3(NPROJ_PAD / 128, 4096 / 128), 256, 0, stream>>>(
        hid_bf, w_inproj, zx, 4096, NPROJ_PAD, 512);

    // 3) conv + dt
    conv_dt_kernel<<<18688, 256, 0, stream>>>(zx, conv_w, conv_b, dt_bias, convout, dtbuf);

    // 4) chunked SSM scan (CHUNK=32; phase2 halves; yp0=ybuf, yp1=Sc reuse)
    scan_phase1<<<2048, 256, 0, stream>>>(convout, dtbuf, A_log, Sc, Ptot);
    scan_combine<<<256, 64, 0, stream>>>(Sc, Ptot, Sinit);
    scan_phase2<<<2048, 128, 0, stream>>>(convout, dtbuf, A_log, Sinit, ybuf, Sc);

    // 5) gated RMSNorm -> bf16
    gated_rms_kernel<<<4096, 256, 0, stream>>>(ybuf, Sc, convout, zx, Dv, norm_w, g_bf);

    // 6) out_proj GEMM, split-K x4 (512 blocks)
    gemm_bt_sk<<<dim3(512 / 128, 4096 / 128, 4), 256, 0, stream>>>(
        g_bf, w_outproj, out2, 4096, 512, 1024, 256);

    // 7) h1 = rms(hidden + out2)
    residual_rms_kernel<<<4096, 128, 0, stream>>>(hid, out2, h1, 512);

    // 8) transpose (B,1024,512) -> (B,512,1024)  [overwrites Sc region - dead]
    transpose_dual_kernel<<<dim3(16, 32, 4), dim3(32, 8), 0, stream>>>(h1, xt_bf, xt_f, 1024, 512);

    // 9) token MLP: t1 = xt @ gu_t^T (704 blocks)
    gemm_bt<<<dim3(5632 / 128, 2048 / 128), 256, 0, stream>>>(xt_bf, w_gut, t1, 2048, 5632, 1024);

    // 10) swiglu -> act1 bf16
    swiglu_kernel<<<22528, 256, 0, stream>>>(t1, act1, 2048, 2816);

    // 11) t2 = act1 @ down_t^T, split-K x4 (512 blocks); zero first
    hipMemsetAsync(t2, 0, (size_t)2048 * 1024 * 4, stream);
    gemm_bt_sk<<<dim3(1024 / 128, 2048 / 128, 4), 256, 0, stream>>>(
        act1, w_downt, t2, 2048, 1024, 2816, 704);

    // 12) x2 = rms(xt_f + t2)
    residual_rms_kernel<<<2048, 256, 0, stream>>>(xt_f, t2, x2, 1024);

    // 13) transpose back (B,512,1024) -> (B,1024,512)
    transpose_dual_kernel<<<dim3(32, 16, 4), dim3(32, 8), 0, stream>>>(x2, h2_bf, h2_f, 512, 1024);

    // 14) channel MLP: t3 = h2 @ gu_m^T (768 blocks)
    gemm_bt<<<dim3(3072 / 128, 4096 / 128), 256, 0, stream>>>(h2_bf, w_gum, t3, 4096, 3072, 512);

    // 15) swiglu -> act2 bf16
    swiglu_kernel<<<24576, 256, 0, stream>>>(t3, act2, 4096, 1536);

    // 16) t4 = act2 @ down_m^T, split-K x4 (512 blocks); zero first
    hipMemsetAsync(t4, 0, (size_t)4096 * 512 * 4, stream);
    gemm_bt_sk<<<dim3(512 / 128, 4096 / 128, 4), 256, 0, stream>>>(
        act2, w_downm, t4, 4096, 512, 1536, 384);

    // 17) out = rms(h2_f + t4)
    residual_rms_kernel<<<4096, 128, 0, stream>>>(h2_f, t4, outp, 512);
}

// Round 9
// 433.032 us; speedup vs baseline: 1.2780x; 1.1243x over previous
//
#include <hip/hip_runtime.h>

// ---------------------------------------------------------------------------
// Mamba2 hybrid block. GEMMs: bf16 MFMA 16x16x32, f32 accumulate, m97-style
// global_load_lds(16B) staging with XOR bank swizzle. Small-N GEMMs use
// split-K x4 into SEPARATE partial buffers (plain stores, no atomics — R7
// showed atomic split-K costs 4x WRITE amplification + RMW fetch); partials
// are summed inside the downstream residual_rms kernel. Scan: 3-phase
// chunked, CHUNK=32, B/C/dt staged in LDS; y per-lane complete.
// R8 BUG FIX: MLP overlay region must hold Sc+Sinit = 67.11 MB; pad is 10 MB
// (R8's 8 MB left Sinit's tail overrunning 1 MB into zx -> absmax 2.2).
// ---------------------------------------------------------------------------

#define BB 4
#define LL 1024
#define DMODEL 512
#define DINNER 1024
#define NHEADS 16
#define HEADDIM 64
#define DSTATE 64
#define CONVDIM 1152        // DINNER + 2*DSTATE
#define NPROJ 2192          // D_IN_PROJ
#define NPROJ_PAD 2304      // padded to multiple of 128
#define INTER_T 2816
#define INTER_M 1536
#define NCHUNK 32
#define CHUNK 32

typedef __bf16 bf16x8 __attribute__((ext_vector_type(8)));
typedef float  f32x4  __attribute__((ext_vector_type(4)));
typedef unsigned short u16;
typedef unsigned int   u32;

__device__ __forceinline__ u16 f2bf(float x) {
    union { float f; u32 u; } v; v.f = x;
    u32 u = v.u;
    return (u16)((u + 0x7fffu + ((u >> 16) & 1u)) >> 16);
}
__device__ __forceinline__ float silu_f(float x) {
    return x / (1.f + __expf(-x));
}

// async global->LDS, 16B per lane; LDS dest is wave-uniform base + lane*16
__device__ __forceinline__ void gld_lds16(const u16* g, u16* l) {
    __builtin_amdgcn_global_load_lds(
        (const __attribute__((address_space(1))) unsigned int*)g,
        (__attribute__((address_space(3))) unsigned int*)l, 16, 0, 0);
}

// --------------------------- block-wide sum --------------------------------
__device__ __forceinline__ float block_sum(float v) {
    #pragma unroll
    for (int off = 32; off > 0; off >>= 1) v += __shfl_xor(v, off, 64);
    __shared__ float red[4];
    int w = threadIdx.x >> 6;
    int nwv = blockDim.x >> 6;
    if ((threadIdx.x & 63) == 0) red[w] = v;
    __syncthreads();
    float tot = red[0];
    for (int i = 1; i < nwv; i++) tot += red[i];
    return tot;
}

// --------------------- f32 -> bf16 convert (all weights + hidden) ----------
#define HID_E      2097152LL   // 4096*512
#define INPROJ_P_E 1179648LL   // 2304*512
#define INPROJ_S_E 1122304LL   // 2192*512
#define OUTPROJ_E   524288LL   // 512*1024
#define GUT_E      5767168LL   // 5632*1024
#define DOWNT_E    2883584LL   // 1024*2816
#define GUM_E      1572864LL   // 3072*512
#define DOWNM_E     786432LL   // 512*1536
#define CONV_TOT_E 14811136LL

__global__ __launch_bounds__(256) void convert_all_kernel(
    const float* __restrict__ s_hid, const float* __restrict__ s_inproj,
    const float* __restrict__ s_outproj, const float* __restrict__ s_gut,
    const float* __restrict__ s_downt, const float* __restrict__ s_gum,
    const float* __restrict__ s_downm, u16* __restrict__ dst)
{
    long long idx = (long long)blockIdx.x * 256 + threadIdx.x;
    long long e = idx * 4;
    if (e >= CONV_TOT_E) return;
    const float* src; long long off, nsrc;
    long long c0 = HID_E;
    long long c1 = c0 + INPROJ_P_E;
    long long c2 = c1 + OUTPROJ_E;
    long long c3 = c2 + GUT_E;
    long long c4 = c3 + DOWNT_E;
    long long c5 = c4 + GUM_E;
    if      (e < c0) { src = s_hid;     off = e;      nsrc = HID_E; }
    else if (e < c1) { src = s_inproj;  off = e - c0; nsrc = INPROJ_S_E; }
    else if (e < c2) { src = s_outproj; off = e - c1; nsrc = OUTPROJ_E; }
    else if (e < c3) { src = s_gut;     off = e - c2; nsrc = GUT_E; }
    else if (e < c4) { src = s_downt;   off = e - c3; nsrc = DOWNT_E; }
    else if (e < c5) { src = s_gum;     off = e - c4; nsrc = GUM_E; }
    else             { src = s_downm;   off = e - c5; nsrc = DOWNM_E; }
    ushort4 r;
    if (off < nsrc) {
        float4 v = *reinterpret_cast<const float4*>(src + off);
        r.x = f2bf(v.x); r.y = f2bf(v.y); r.z = f2bf(v.z); r.w = f2bf(v.w);
    } else {
        r.x = 0; r.y = 0; r.z = 0; r.w = 0;
    }
    *reinterpret_cast<ushort4*>(dst + e) = r;
}

// ----------------------------- bf16 MFMA GEMM ------------------------------
// C[M,N] = A[M,K] * W[N,K]^T. 128x128 tile, 4 waves of 64x64 (4x4 MFMAs).
// global_load_lds staging (no pad; XOR chunk swizzle vs bank conflicts).
// SK: write this slice's tile to C + slice*M*N (plain stores; summed later).
template<bool SK>
__device__ __forceinline__ void gemm_bt_body(
    const u16* __restrict__ A, const u16* __restrict__ W,
    float* __restrict__ C, int M, int N, int K, int kLen)
{
    __shared__ u16 As[128 * 32];
    __shared__ u16 Bs[128 * 32];
    int tid = threadIdx.x;
    int m0 = blockIdx.y * 128, n0 = blockIdx.x * 128;
    int kBase = SK ? blockIdx.z * kLen : 0;
    float* Cw = SK ? C + (size_t)blockIdx.z * M * N : C;
    int wave = tid >> 6, lane = tid & 63;
    int wm = (wave >> 1) * 64, wn = (wave & 1) * 64;
    int lrow = lane & 15;
    int kq = lane >> 4;
    int kx = (lrow & 3) ^ ((lrow >> 2) & 3);
    int ko = (kq ^ kx) * 8;           // swizzled LDS chunk offset for frags

    int rL = lane >> 2, cL = lane & 3;
    int cG = cL ^ ((rL & 3) ^ ((rL >> 2) & 3));
    int R0 = wave * 32 + rL;
    int R1 = R0 + 16;
    const u16* gA0 = A + (size_t)(m0 + R0) * K + kBase + cG * 8;
    const u16* gA1 = A + (size_t)(m0 + R1) * K + kBase + cG * 8;
    const u16* gB0 = W + (size_t)(n0 + R0) * K + kBase + cG * 8;
    const u16* gB1 = W + (size_t)(n0 + R1) * K + kBase + cG * 8;
    u16* lA0 = &As[(wave * 32) * 32];
    u16* lA1 = &As[(wave * 32 + 16) * 32];
    u16* lB0 = &Bs[(wave * 32) * 32];
    u16* lB1 = &Bs[(wave * 32 + 16) * 32];

    f32x4 acc[4][4];
    #pragma unroll
    for (int i = 0; i < 4; i++)
        #pragma unroll
        for (int j = 0; j < 4; j++) {
            acc[i][j][0] = 0.f; acc[i][j][1] = 0.f;
            acc[i][j][2] = 0.f; acc[i][j][3] = 0.f;
        }

    for (int kt = 0; kt < kLen; kt += 32) {
        __syncthreads();
        gld_lds16(gA0 + kt, lA0);
        gld_lds16(gA1 + kt, lA1);
        gld_lds16(gB0 + kt, lB0);
        gld_lds16(gB1 + kt, lB1);
        __syncthreads();
        bf16x8 af[4], bfr[4];
        #pragma unroll
        for (int i = 0; i < 4; i++) {
            af[i]  = *reinterpret_cast<const bf16x8*>(&As[(wm + i * 16 + lrow) * 32 + ko]);
            bfr[i] = *reinterpret_cast<const bf16x8*>(&Bs[(wn + i * 16 + lrow) * 32 + ko]);
        }
        #pragma unroll
        for (int i = 0; i < 4; i++)
            #pragma unroll
            for (int j = 0; j < 4; j++)
                acc[i][j] = __builtin_amdgcn_mfma_f32_16x16x32_bf16(af[i], bfr[j], acc[i][j], 0, 0, 0);
    }

    // C/D layout: col = lane&15, row = (lane>>4)*4 + reg
    int rbase = m0 + wm + kq * 4;
    int cbase = n0 + wn + lrow;
    #pragma unroll
    for (int i = 0; i < 4; i++)
        #pragma unroll
        for (int j = 0; j < 4; j++)
            #pragma unroll
            for (int r = 0; r < 4; r++)
                Cw[(size_t)(rbase + i * 16 + r) * N + cbase + j * 16] = acc[i][j][r];
}

__global__ __launch_bounds__(256) void gemm_bt(
    const u16* __restrict__ A, const u16* __restrict__ W,
    float* __restrict__ C, int M, int N, int K)
{
    gemm_bt_body<false>(A, W, C, M, N, K, K);
}

__global__ __launch_bounds__(256) void gemm_bt_sk(
    const u16* __restrict__ A, const u16* __restrict__ W,
    float* __restrict__ C, int M, int N, int K, int kLen)
{
    gemm_bt_body<true>(A, W, C, M, N, K, kLen);
}

// ----------------- conv (depthwise, causal, width 4) + dt ------------------
__global__ __launch_bounds__(256) void conv_dt_kernel(
    const float* __restrict__ zx, const float* __restrict__ conv_w,
    const float* __restrict__ conv_b, const float* __restrict__ dt_bias,
    float* __restrict__ convout, float* __restrict__ dtbuf)
{
    int idx = blockIdx.x * 256 + threadIdx.x;   // over 4096*1168
    int bl = idx / 1168;
    int c  = idx - bl * 1168;
    int l  = bl & (LL - 1);
    if (c < CONVDIM) {
        const float* col = zx + (size_t)bl * NPROJ_PAD + DINNER + c;
        float acc = conv_b[c];
        #pragma unroll
        for (int i = 0; i < 4; i++) {
            int lt = l - 3 + i;
            float v = (lt >= 0) ? col[(long long)(lt - l) * NPROJ_PAD] : 0.f;
            acc = fmaf(v, conv_w[c * 4 + i], acc);
        }
        convout[(size_t)bl * CONVDIM + c] = silu_f(acc);
    } else {
        int h = c - CONVDIM;
        float v = zx[(size_t)bl * NPROJ_PAD + 2176 + h] + dt_bias[h];
        float sp = (v > 20.f) ? v : log1pf(__expf(v));
        dtbuf[(size_t)bl * NHEADS + h] = sp;
    }
}

// ----------------------- chunked SSM scan: phase 1 -------------------------
// block = (b*16+h)*32 + c, 256 thr; wave = nq (16 states/lane); B/dt staged
// in LDS once per chunk. 32 steps from zero state -> Sc, Ptot.
__global__ __launch_bounds__(256) void scan_phase1(
    const float* __restrict__ convout, const float* __restrict__ dtbuf,
    const float* __restrict__ A_log, float* __restrict__ Sc,
    float* __restrict__ Ptot)
{
    __shared__ float Blds[CHUNK * 64];   // 8 KB
    __shared__ float dtl[CHUNK];
    int blk = blockIdx.x;
    int c   = blk & 31;
    int bh  = blk >> 5;
    int b = bh >> 4, h = bh & 15;
    int nq = threadIdx.x >> 6;
    int p  = threadIdx.x & 63;
    size_t base = ((size_t)b * LL + (size_t)c * CHUNK) * CONVDIM;

    const float* Bsrc = convout + base + DINNER;
    #pragma unroll
    for (int i = threadIdx.x; i < CHUNK * 16; i += 256) {   // 512 float4s
        int t = i >> 4, q = i & 15;
        *reinterpret_cast<float4*>(&Blds[t * 64 + q * 4]) =
            *reinterpret_cast<const float4*>(&Bsrc[(size_t)t * CONVDIM + q * 4]);
    }
    const float* db = dtbuf + ((size_t)b * LL + (size_t)c * CHUNK) * NHEADS + h;
    if (threadIdx.x < CHUNK) dtl[threadIdx.x] = db[(size_t)threadIdx.x * NHEADS];
    __syncthreads();

    float Ah = -__expf(A_log[h]);
    const float* xb = convout + base + h * HEADDIM + p;

    float s[16];
    #pragma unroll
    for (int j = 0; j < 16; j++) s[j] = 0.f;
    float dtsum = 0.f;

    float dtc = dtl[0], xvc = xb[0];
    float Bv[16];
    #pragma unroll
    for (int j = 0; j < 16; j++) Bv[j] = Blds[nq * 16 + j];

    for (int t = 0; t < CHUNK; ++t) {
        float dt = dtc, xv = xvc;
        float Bl[16];
        #pragma unroll
        for (int j = 0; j < 16; j++) Bl[j] = Bv[j];
        int tn = (t < CHUNK - 1) ? t + 1 : CHUNK - 1;
        dtc = dtl[tn];
        xvc = xb[(size_t)tn * CONVDIM];
        #pragma unroll
        for (int j = 0; j < 16; j++) Bv[j] = Blds[tn * 64 + nq * 16 + j];
        float dA = __expf(dt * Ah);
        dtsum += dt;
        float coef = dt * xv;
        #pragma unroll
        for (int j = 0; j < 16; j++) s[j] = fmaf(s[j], dA, coef * Bl[j]);
    }
    float* So = Sc + ((size_t)(bh * 4 + nq) * NCHUNK + c) * 1024 + p * 16;
    #pragma unroll
    for (int q = 0; q < 4; q++) {
        float4 v; v.x = s[q*4]; v.y = s[q*4+1]; v.z = s[q*4+2]; v.w = s[q*4+3];
        *reinterpret_cast<float4*>(So + q * 4) = v;
    }
    if (nq == 0 && p == 0) Ptot[bh * NCHUNK + c] = __expf(Ah * dtsum);
}

// ----------------------- chunked SSM scan: phase 2 -------------------------
// block = (b*16+h)*4 + nq (256 blocks); sequential carry over 32 chunks.
__global__ __launch_bounds__(64) void scan_combine(
    const float* __restrict__ Sc, const float* __restrict__ Ptot,
    float* __restrict__ Sinit)
{
    int blk = blockIdx.x;
    int bh = blk >> 2;
    int p = threadIdx.x;
    float carry[16];
    #pragma unroll
    for (int j = 0; j < 16; j++) carry[j] = 0.f;
    for (int c = 0; c < NCHUNK; ++c) {
        size_t row = ((size_t)blk * NCHUNK + c) * 1024 + p * 16;
        float* o = Sinit + row;
        #pragma unroll
        for (int j = 0; j < 16; j++) o[j] = carry[j];
        float P = Ptot[bh * NCHUNK + c];
        const float* si = Sc + row;
        #pragma unroll
        for (int j = 0; j < 16; j++) carry[j] = fmaf(carry[j], P, si[j]);
    }
}

// ----------------------- chunked SSM scan: phase 3 -------------------------
// block = (b*16+h)*32 + c, 128 thr; wave = nh (32 states/lane). Full B+C tile
// (32 steps x 128 floats) + dt staged in LDS; y per-lane complete -> plain
// coalesced stores into partial buffers yp0/yp1 (summed by gated_rms).
__global__ __launch_bounds__(128) void scan_phase2(
    const float* __restrict__ convout, const float* __restrict__ dtbuf,
    const float* __restrict__ A_log, const float* __restrict__ Sinit,
    float* __restrict__ yp0, float* __restrict__ yp1)
{
    __shared__ float BClds[CHUNK * 128];   // 16 KB
    __shared__ float dtl[CHUNK];
    int blk = blockIdx.x;
    int c   = blk & 31;
    int bh  = blk >> 5;
    int b = bh >> 4, h = bh & 15;
    int nh = threadIdx.x >> 6;
    int p  = threadIdx.x & 63;
    size_t base = ((size_t)b * LL + (size_t)c * CHUNK) * CONVDIM;

    const float* BCsrc = convout + base + DINNER;
    #pragma unroll
    for (int i = threadIdx.x; i < CHUNK * 32; i += 128) {   // 1024 float4s
        int t = i >> 5, q = i & 31;
        *reinterpret_cast<float4*>(&BClds[t * 128 + q * 4]) =
            *reinterpret_cast<const float4*>(&BCsrc[(size_t)t * CONVDIM + q * 4]);
    }
    const float* db = dtbuf + ((size_t)b * LL + (size_t)c * CHUNK) * NHEADS + h;
    if (threadIdx.x < CHUNK) dtl[threadIdx.x] = db[(size_t)threadIdx.x * NHEADS];
    __syncthreads();

    float Ah = -__expf(A_log[h]);
    const float* xb = convout + base + h * HEADDIM + p;
    float* yb = (nh ? yp1 : yp0)
              + ((size_t)b * LL + (size_t)c * CHUNK) * DINNER + h * HEADDIM + p;

    float s[32];
    {   // states j<16 from quarter 2*nh, j>=16 from quarter 2*nh+1
        const float* si0 = Sinit + ((size_t)(bh * 4 + nh * 2)     * NCHUNK + c) * 1024 + p * 16;
        const float* si1 = Sinit + ((size_t)(bh * 4 + nh * 2 + 1) * NCHUNK + c) * 1024 + p * 16;
        #pragma unroll
        for (int j = 0; j < 16; j++) { s[j] = si0[j]; s[16 + j] = si1[j]; }
    }

    float dtc = dtl[0], xvc = xb[0];
    float Bv[32], Cv[32];
    #pragma unroll
    for (int j = 0; j < 32; j++) {
        Bv[j] = BClds[nh * 32 + j];
        Cv[j] = BClds[64 + nh * 32 + j];
    }

    for (int t = 0; t < CHUNK; ++t) {
        float dt = dtc, xv = xvc;
        float Bl[32], Cl[32];
        #pragma unroll
        for (int j = 0; j < 32; j++) { Bl[j] = Bv[j]; Cl[j] = Cv[j]; }
        int tn = (t < CHUNK - 1) ? t + 1 : CHUNK - 1;
        dtc = dtl[tn];
        xvc = xb[(size_t)tn * CONVDIM];
        #pragma unroll
        for (int j = 0; j < 32; j++) {
            Bv[j] = BClds[tn * 128 + nh * 32 + j];
            Cv[j] = BClds[tn * 128 + 64 + nh * 32 + j];
        }
        float dA = __expf(dt * Ah);
        float coef = dt * xv;
        float yacc = 0.f;
        #pragma unroll
        for (int j = 0; j < 32; j++) {
            s[j] = fmaf(s[j], dA, coef * Bl[j]);
            yacc = fmaf(s[j], Cl[j], yacc);
        }
        yb[(size_t)t * DINNER] = yacc;    // plain store, 64 lanes coalesced
    }
}

// ------------- gated RMSNorm (yp0+yp1+xD)*silu(z), bf16 out ----------------
__global__ __launch_bounds__(256) void gated_rms_kernel(
    const float* __restrict__ yp0, const float* __restrict__ yp1,
    const float* __restrict__ convout, const float* __restrict__ zx,
    const float* __restrict__ Dv, const float* __restrict__ norm_w,
    u16* __restrict__ gout)
{
    int bl = blockIdx.x;
    int c = threadIdx.x * 4;
    float4 y0 = *reinterpret_cast<const float4*>(yp0 + (size_t)bl * DINNER + c);
    float4 y1 = *reinterpret_cast<const float4*>(yp1 + (size_t)bl * DINNER + c);
    float4 xv = *reinterpret_cast<const float4*>(convout + (size_t)bl * CONVDIM + c);
    float4 zv = *reinterpret_cast<const float4*>(zx + (size_t)bl * NPROJ_PAD + c);
    float Dh = Dv[c >> 6];
    float g0 = (y0.x + y1.x + xv.x * Dh) * silu_f(zv.x);
    float g1 = (y0.y + y1.y + xv.y * Dh) * silu_f(zv.y);
    float g2 = (y0.z + y1.z + xv.z * Dh) * silu_f(zv.z);
    float g3 = (y0.w + y1.w + xv.w * Dh) * silu_f(zv.w);
    float tot = block_sum(g0 * g0 + g1 * g1 + g2 * g2 + g3 * g3);
    float sc = rsqrtf(tot * (1.f / DINNER) + 1e-5f);
    float4 nw = *reinterpret_cast<const float4*>(norm_w + c);
    ushort4 o;
    o.x = f2bf(g0 * sc * nw.x); o.y = f2bf(g1 * sc * nw.y);
    o.z = f2bf(g2 * sc * nw.z); o.w = f2bf(g3 * sc * nw.w);
    *reinterpret_cast<ushort4*>(gout + (size_t)bl * DINNER + c) = o;
}

// ---- residual + 4 split-K partials + RMSNorm (no weight), f32 out ---------
// blockDim = ncols/4; partial s at pbuf + s*rows*ncols
__global__ void residual_rms_sk_kernel(
    const float* __restrict__ a, const float* __restrict__ pbuf,
    float* __restrict__ outf, int ncols, int rows)
{
    int row = blockIdx.x;
    int c = threadIdx.x * 4;
    size_t slice = (size_t)rows * ncols;
    size_t off = (size_t)row * ncols + c;
    float4 va = *reinterpret_cast<const float4*>(a + off);
    float4 p0 = *reinterpret_cast<const float4*>(pbuf + off);
    float4 p1 = *reinterpret_cast<const float4*>(pbuf + slice + off);
    float4 p2 = *reinterpret_cast<const float4*>(pbuf + 2 * slice + off);
    float4 p3 = *reinterpret_cast<const float4*>(pbuf + 3 * slice + off);
    float v0 = va.x + ((p0.x + p1.x) + (p2.x + p3.x));
    float v1 = va.y + ((p0.y + p1.y) + (p2.y + p3.y));
    float v2 = va.z + ((p0.z + p1.z) + (p2.z + p3.z));
    float v3 = va.w + ((p0.w + p1.w) + (p2.w + p3.w));
    float tot = block_sum(v0 * v0 + v1 * v1 + v2 * v2 + v3 * v3);
    float sc = rsqrtf(tot / (float)ncols + 1e-5f);
    float4 o; o.x = v0 * sc; o.y = v1 * sc; o.z = v2 * sc; o.w = v3 * sc;
    *reinterpret_cast<float4*>(outf + off) = o;
}

// ------------- transpose per batch: in (R,C) -> out (C,R), dual write ------
__global__ __launch_bounds__(256) void transpose_dual_kernel(
    const float* __restrict__ in, u16* __restrict__ outb,
    float* __restrict__ outf, int R, int C)
{
    __shared__ float tile[32][33];
    int b = blockIdx.z;
    int c0 = blockIdx.x * 32, r0 = blockIdx.y * 32;
    const float* ip = in + (size_t)b * R * C;
    for (int i = threadIdx.y; i < 32; i += 8)
        tile[i][threadIdx.x] = ip[(size_t)(r0 + i) * C + c0 + threadIdx.x];
    __syncthreads();
    size_t ob = (size_t)b * R * C;
    for (int i = threadIdx.y; i < 32; i += 8) {
        float v = tile[threadIdx.x][i];
        size_t oi = ob + (size_t)(c0 + i) * R + r0 + threadIdx.x;
        outf[oi] = v;
        outb[oi] = f2bf(v);
    }
}

// ------------------------------ SwiGLU -------------------------------------
__global__ __launch_bounds__(256) void swiglu_kernel(
    const float* __restrict__ t, u16* __restrict__ act, int rows, int inter)
{
    int idx = blockIdx.x * 256 + threadIdx.x;
    if (idx >= rows * inter) return;
    int r = idx / inter, c = idx - r * inter;
    float g = t[(size_t)r * 2 * inter + c];
    float u = t[(size_t)r * 2 * inter + inter + c];
    act[idx] = f2bf(silu_f(g) * u);
}

// ---------------------------------------------------------------------------
extern "C" void kernel_launch(void* const* d_in, const int* in_sizes, int n_in,
                              void* d_out, int out_size, void* d_ws, size_t ws_size,
                              hipStream_t stream)
{
    const float* hid      = (const float*)d_in[0];
    const float* in_proj  = (const float*)d_in[1];
    const float* conv_w   = (const float*)d_in[2];
    const float* conv_b   = (const float*)d_in[3];
    const float* dt_bias  = (const float*)d_in[4];
    const float* A_log    = (const float*)d_in[5];
    const float* Dv       = (const float*)d_in[6];
    const float* norm_w   = (const float*)d_in[7];
    const float* out_proj = (const float*)d_in[8];
    const float* gu_t     = (const float*)d_in[9];
    const float* down_t   = (const float*)d_in[10];
    const float* gu_m     = (const float*)d_in[11];
    const float* down_m   = (const float*)d_in[12];
    float* outp = (float*)d_out;

    char* ws = (char*)d_ws;
    u16* bf        = (u16*)ws;
    u16* hid_bf    = bf;
    u16* w_inproj  = bf + HID_E;
    u16* w_outproj = w_inproj + INPROJ_P_E;
    u16* w_gut     = w_outproj + OUTPROJ_E;
    u16* w_downt   = w_gut + GUT_E;
    u16* w_gum     = w_downt + DOWNT_E;
    u16* w_downm   = w_gum + GUM_E;
    size_t o = (size_t)(CONV_TOT_E * 2);
    auto alloc = [&](size_t bytes) { size_t r = o; o = (o + bytes + 255) & ~(size_t)255; return r; };
    size_t dt_off  = alloc(4096 * 16 * 4);
    size_t g_off   = alloc((size_t)4096 * 1024 * 2);
    size_t h1_off  = alloc((size_t)4096 * 512 * 4);
    size_t Pt_off  = alloc(2048 * 4);
    // ---- MLP region (live step 8+); Sc/Sinit OVERLAY it (live steps 4-5).
    // Region must hold Sc+Sinit = 2 x 8192*1024*4 = 67,108,864 B.
    // Sum below (xtb..act2) = 57,671,680 B -> pad 10 MB => 68,157,440 B. OK.
    size_t xtb_off = alloc((size_t)2048 * 1024 * 2);
    size_t xtf_off = alloc((size_t)2048 * 1024 * 4);
    size_t act1_off= alloc((size_t)2048 * 2816 * 2);
    size_t x2_off  = alloc((size_t)2048 * 1024 * 4);
    size_t h2b_off = alloc((size_t)4096 * 512 * 2);
    size_t h2f_off = alloc((size_t)4096 * 512 * 4);
    size_t act2_off= alloc((size_t)4096 * 1536 * 2);
    size_t pad_off = alloc((size_t)10 * 1024 * 1024);
    size_t Sc_off  = xtb_off;                          // 33.55 MB
    size_t Si_off  = xtb_off + (size_t)8192 * 1024 * 4;// 33.55 MB
    (void)pad_off;
    // overlay region R_off: {zxbcdt, convout, yp0} live until gated_rms;
    // then split-K partials (33.5 MB) / t1 (46 MB) / t3 (50 MB) time-share it.
    size_t R_off   = o;
    size_t zx_off  = R_off;
    size_t cv_off  = zx_off + (size_t)4096 * NPROJ_PAD * 4;
    size_t y_off   = cv_off + (size_t)4096 * CONVDIM * 4;
    size_t t1_off  = R_off;
    size_t t3_off  = R_off;
    size_t sk_off  = R_off;

    float* zx      = (float*)(ws + zx_off);
    float* convout = (float*)(ws + cv_off);
    float* ybuf    = (float*)(ws + y_off);           // yp0
    float* dtbuf   = (float*)(ws + dt_off);
    u16*   g_bf    = (u16*)(ws + g_off);
    float* h1      = (float*)(ws + h1_off);
    u16*   xt_bf   = (u16*)(ws + xtb_off);
    float* xt_f    = (float*)(ws + xtf_off);
    float* t1      = (float*)(ws + t1_off);
    u16*   act1    = (u16*)(ws + act1_off);
    float* x2      = (float*)(ws + x2_off);
    u16*   h2_bf   = (u16*)(ws + h2b_off);
    float* h2_f    = (float*)(ws + h2f_off);
    float* t3      = (float*)(ws + t3_off);
    u16*   act2    = (u16*)(ws + act2_off);
    float* skbuf   = (float*)(ws + sk_off);          // split-K partials x4
    float* Sc      = (float*)(ws + Sc_off);          // yp1 after scan_combine
    float* Sinit   = (float*)(ws + Si_off);
    float* Ptot    = (float*)(ws + Pt_off);

    // 1) convert weights + hidden to bf16
    convert_all_kernel<<<14464, 256, 0, stream>>>(
        hid, in_proj, out_proj, gu_t, down_t, gu_m, down_m, bf);

    // 2) zxbcdt = hidden @ in_proj^T  (576 blocks)
    gemm_bt<<<dim3(NPROJ_PAD / 128, 4096 / 128), 256, 0, stream>>>(
        hid_bf, w_inproj, zx, 4096, NPROJ_PAD, 512);

    // 3) conv + dt
    conv_dt_kernel<<<18688, 256, 0, stream>>>(zx, conv_w, conv_b, dt_bias, convout, dtbuf);

    // 4) chunked SSM scan (CHUNK=32; phase2 halves; yp0=ybuf, yp1=Sc reuse)
    scan_phase1<<<2048, 256, 0, stream>>>(convout, dtbuf, A_log, Sc, Ptot);
    scan_combine<<<256, 64, 0, stream>>>(Sc, Ptot, Sinit);
    scan_phase2<<<2048, 128, 0, stream>>>(convout, dtbuf, A_log, Sinit, ybuf, Sc);

    // 5) gated RMSNorm -> bf16  (zx/convout/ybuf dead after this)
    gated_rms_kernel<<<4096, 256, 0, stream>>>(ybuf, Sc, convout, zx, Dv, norm_w, g_bf);

    // 6) out_proj GEMM, split-K x4 -> partials in skbuf (512 blocks)
    gemm_bt_sk<<<dim3(512 / 128, 4096 / 128, 4), 256, 0, stream>>>(
        g_bf, w_outproj, skbuf, 4096, 512, 1024, 256);

    // 7) h1 = rms(hidden + sum partials)
    residual_rms_sk_kernel<<<4096, 128, 0, stream>>>(hid, skbuf, h1, 512, 4096);

    // 8) transpose (B,1024,512) -> (B,512,1024)  [overwrites Sc region - dead]
    transpose_dual_kernel<<<dim3(16, 32, 4), dim3(32, 8), 0, stream>>>(h1, xt_bf, xt_f, 1024, 512);

    // 9) token MLP: t1 = xt @ gu_t^T (704 blocks)  [t1 overwrites skbuf - dead]
    gemm_bt<<<dim3(5632 / 128, 2048 / 128), 256, 0, stream>>>(xt_bf, w_gut, t1, 2048, 5632, 1024);

    // 10) swiglu -> act1 bf16
    swiglu_kernel<<<22528, 256, 0, stream>>>(t1, act1, 2048, 2816);

    // 11) down_t GEMM, split-K x4 -> partials in skbuf (512 blocks) [t1 dead]
    gemm_bt_sk<<<dim3(1024 / 128, 2048 / 128, 4), 256, 0, stream>>>(
        act1, w_downt, skbuf, 2048, 1024, 2816, 704);

    // 12) x2 = rms(xt_f + sum partials)
    residual_rms_sk_kernel<<<2048, 256, 0, stream>>>(xt_f, skbuf, x2, 1024, 2048);

    // 13) transpose back (B,512,1024) -> (B,1024,512)
    transpose_dual_kernel<<<dim3(32, 16, 4), dim3(32, 8), 0, stream>>>(x2, h2_bf, h2_f, 512, 1024);

    // 14) channel MLP: t3 = h2 @ gu_m^T (768 blocks) [t3 overwrites skbuf - dead]
    gemm_bt<<<dim3(3072 / 128, 4096 / 128), 256, 0, stream>>>(h2_bf, w_gum, t3, 4096, 3072, 512);

    // 15) swiglu -> act2 bf16
    swiglu_kernel<<<24576, 256, 0, stream>>>(t3, act2, 4096, 1536);

    // 16) down_m GEMM, split-K x4 -> partials in skbuf (512 blocks) [t3 dead]
    gemm_bt_sk<<<dim3(512 / 128, 4096 / 128, 4), 256, 0, stream>>>(
        act2, w_downm, skbuf, 4096, 512, 1536, 384);

    // 17) out = rms(h2_f + sum partials)
    residual_rms_sk_kernel<<<4096, 128, 0, stream>>>(h2_f, skbuf, outp, 512, 4096);
}